// Round 2
// baseline (1842.689 us; speedup 1.0000x reference)
//
#include <hip/hip_runtime.h>
#include <hip/hip_bf16.h>

constexpr int NB = 4;      // batch
constexpr int NN = 4096;   // nodes
constexpr int CC = 64;     // channels
constexpr int NH = 4;      // heads
constexpr int DH = 16;     // head dim

enum { EPI_PLAIN = 0, EPI_HEADS = 1, EPI_RESID = 2, EPI_RELU = 3 };

// C[M][NC] = A[M][K] @ W[NC][K]^T + bias, with epilogue variants. All f32.
// Block: 256 threads, 64 rows. K chunked by 64. LDS layouts are k-major
// (As[kk][r], Ws[kk][c]) so compute-phase float4 reads are 2-way (free).
template<int K, int NC, int EPI>
__global__ __launch_bounds__(256) void gemm_k(
    const float* __restrict__ Ain,
    const float* __restrict__ W,
    const float* __restrict__ bias,
    float* __restrict__ out,
    const float* __restrict__ resid,
    float scale)
{
  constexpr int CPT = NC / 16;  // cols per thread (4, 8)
  __shared__ __align__(16) float As[64][68];
  __shared__ __align__(16) float Ws[64][NC + 4];

  const int tid = threadIdx.x;
  const int rowbase = blockIdx.x * 64;
  const int r4 = (tid & 15) * 4;        // 4 consecutive rows
  const int cg = (tid >> 4) * CPT;      // CPT consecutive cols

  float acc[4][CPT];
  #pragma unroll
  for (int i = 0; i < 4; ++i)
    #pragma unroll
    for (int j = 0; j < CPT; ++j) acc[i][j] = 0.f;

  for (int k0 = 0; k0 < K; k0 += 64) {
    if (k0) __syncthreads();
    // stage W chunk (transpose to k-major)
    #pragma unroll
    for (int i = 0; i < (NC * 64) / 256; ++i) {
      int idx = tid + i * 256;
      int c2 = idx >> 6, kk = idx & 63;
      Ws[kk][c2] = W[(size_t)c2 * K + k0 + kk];
    }
    // stage A chunk (transpose to k-major)
    #pragma unroll
    for (int i = 0; i < 16; ++i) {
      int idx = tid + i * 256;
      int r = idx >> 6, kk = idx & 63;
      As[kk][r] = Ain[(size_t)(rowbase + r) * K + k0 + kk];
    }
    __syncthreads();

    #pragma unroll 4
    for (int kk = 0; kk < 64; ++kk) {
      const float4 a = *(const float4*)&As[kk][r4];
      const float av[4] = {a.x, a.y, a.z, a.w};
      #pragma unroll
      for (int cj = 0; cj < CPT / 4; ++cj) {
        const float4 wv4 = *(const float4*)&Ws[kk][cg + cj * 4];
        const float wv[4] = {wv4.x, wv4.y, wv4.z, wv4.w};
        #pragma unroll
        for (int ri = 0; ri < 4; ++ri)
          #pragma unroll
          for (int ci = 0; ci < 4; ++ci)
            acc[ri][cj * 4 + ci] = fmaf(av[ri], wv[ci], acc[ri][cj * 4 + ci]);
      }
    }
  }

  float bi[CPT];
  #pragma unroll
  for (int j = 0; j < CPT; ++j) bi[j] = bias[cg + j];

  #pragma unroll
  for (int ri = 0; ri < 4; ++ri) {
    const int row = rowbase + r4 + ri;
    #pragma unroll
    for (int j = 0; j < CPT; ++j) {
      float v = acc[ri][j] + bi[j];
      const int c2 = cg + j;
      if constexpr (EPI == EPI_RELU) v = fmaxf(v, 0.f);
      if constexpr (EPI == EPI_RESID) v += resid[(size_t)row * NC + c2];
      if constexpr (EPI == EPI_HEADS) {
        // scatter to [b][h][n][d] f32, with optional pre-scale (q: 0.25)
        v *= scale;
        const size_t oi =
            ((size_t)((row >> 12) * NH + (c2 >> 4)) * NN + (row & (NN - 1))) * DH + (c2 & (DH - 1));
        out[oi] = v;
      } else {
        out[(size_t)row * NC + c2] = v;
      }
    }
  }
}

// Flash-style attention, one thread per (b,h,row). q pre-scaled by 1/sqrt(Dh).
// K/V rows are read with all-lanes-same-address (L1 broadcast); per (b,h) the
// K+V working set is 512 KB -> L2-resident across the 16 row-blocks sharing it.
// No max-subtraction: scores ~ N(0,1); exp cannot overflow f32 here and the
// normalized result is mathematically identical to softmax.
__global__ __launch_bounds__(256) void attn_k(
    const float* __restrict__ qb, const float* __restrict__ kb,
    const float* __restrict__ vb, float* __restrict__ ob)
{
  const int t = blockIdx.x * 256 + threadIdx.x;  // 0..65535
  const int bh = t >> 12;
  const int n = t & (NN - 1);
  const float4* __restrict__ qp = (const float4*)(qb + (size_t)t * DH);
  const float4* __restrict__ kp = (const float4*)(kb + (size_t)bh * NN * DH);
  const float4* __restrict__ vp = (const float4*)(vb + (size_t)bh * NN * DH);

  const float4 q0 = qp[0], q1 = qp[1], q2 = qp[2], q3 = qp[3];
  float4 o0 = {0,0,0,0}, o1 = {0,0,0,0}, o2 = {0,0,0,0}, o3 = {0,0,0,0};
  float ssum = 0.f;

  #pragma unroll 2
  for (int j = 0; j < NN; ++j) {
    const float4 ka = kp[j * 4 + 0];
    const float4 kc = kp[j * 4 + 1];
    const float4 ke = kp[j * 4 + 2];
    const float4 kg = kp[j * 4 + 3];
    float d0 = fmaf(ka.w, q0.w, fmaf(ka.z, q0.z, fmaf(ka.y, q0.y, ka.x * q0.x)));
    float d1 = fmaf(kc.w, q1.w, fmaf(kc.z, q1.z, fmaf(kc.y, q1.y, kc.x * q1.x)));
    float d2 = fmaf(ke.w, q2.w, fmaf(ke.z, q2.z, fmaf(ke.y, q2.y, ke.x * q2.x)));
    float d3 = fmaf(kg.w, q3.w, fmaf(kg.z, q3.z, fmaf(kg.y, q3.y, kg.x * q3.x)));
    const float p = __expf((d0 + d1) + (d2 + d3));
    ssum += p;
    const float4 va = vp[j * 4 + 0];
    const float4 vc = vp[j * 4 + 1];
    const float4 ve = vp[j * 4 + 2];
    const float4 vg = vp[j * 4 + 3];
    o0.x = fmaf(p, va.x, o0.x); o0.y = fmaf(p, va.y, o0.y);
    o0.z = fmaf(p, va.z, o0.z); o0.w = fmaf(p, va.w, o0.w);
    o1.x = fmaf(p, vc.x, o1.x); o1.y = fmaf(p, vc.y, o1.y);
    o1.z = fmaf(p, vc.z, o1.z); o1.w = fmaf(p, vc.w, o1.w);
    o2.x = fmaf(p, ve.x, o2.x); o2.y = fmaf(p, ve.y, o2.y);
    o2.z = fmaf(p, ve.z, o2.z); o2.w = fmaf(p, ve.w, o2.w);
    o3.x = fmaf(p, vg.x, o3.x); o3.y = fmaf(p, vg.y, o3.y);
    o3.z = fmaf(p, vg.z, o3.z); o3.w = fmaf(p, vg.w, o3.w);
  }

  const float inv = 1.f / ssum;
  float* op = ob + ((size_t)(bh >> 2) * NN + n) * CC + (bh & 3) * DH;
  ((float4*)op)[0] = make_float4(o0.x * inv, o0.y * inv, o0.z * inv, o0.w * inv);
  ((float4*)op)[1] = make_float4(o1.x * inv, o1.y * inv, o1.z * inv, o1.w * inv);
  ((float4*)op)[2] = make_float4(o2.x * inv, o2.y * inv, o2.z * inv, o2.w * inv);
  ((float4*)op)[3] = make_float4(o3.x * inv, o3.y * inv, o3.z * inv, o3.w * inv);
}

// BatchNorm over the node axis per (b, c); biased var, EPS=1e-5. One block per
// (b, c) column; optional fused tanh. Safe in-place (each thread read-then-
// writes only its own elements after the block barrier).
__global__ __launch_bounds__(256) void bn_k(
    const float* __restrict__ in, const float* __restrict__ g,
    const float* __restrict__ b, float* __restrict__ out, int do_tanh)
{
  const int bb = blockIdx.x >> 6;
  const int c = blockIdx.x & 63;
  const float* base = in + (size_t)bb * NN * CC + c;
  float s = 0.f, sq = 0.f;
  #pragma unroll
  for (int i = 0; i < 16; ++i) {
    const float v = base[(size_t)(threadIdx.x + i * 256) * CC];
    s += v; sq += v * v;
  }
  #pragma unroll
  for (int off = 32; off; off >>= 1) {
    s += __shfl_down(s, off);
    sq += __shfl_down(sq, off);
  }
  __shared__ float red[8];
  const int wid = threadIdx.x >> 6;
  if ((threadIdx.x & 63) == 0) { red[wid] = s; red[wid + 4] = sq; }
  __syncthreads();
  const float ts = red[0] + red[1] + red[2] + red[3];
  const float tq = red[4] + red[5] + red[6] + red[7];
  const float mean = ts * (1.f / NN);
  const float var = tq * (1.f / NN) - mean * mean;
  const float rstd = rsqrtf(var + 1e-5f);
  const float scale = g[c] * rstd;
  const float shift = b[c] - mean * scale;
  float* ob = out + (size_t)bb * NN * CC + c;
  for (int i = 0; i < 16; ++i) {
    const size_t idx = (size_t)(threadIdx.x + i * 256) * CC;
    const float v = base[idx] * scale + shift;
    ob[idx] = do_tanh ? tanhf(v) : v;
  }
}

extern "C" void kernel_launch(void* const* d_in, const int* in_sizes, int n_in,
                              void* d_out, int out_size, void* d_ws, size_t ws_size,
                              hipStream_t stream)
{
  const float* inp  = (const float*)d_in[0];
  // d_in[1] = adj: unused (conv=None; only gates the always-applied tanh)
  const float* Wp   = (const float*)d_in[2];
  const float* bp   = (const float*)d_in[3];
  const float* Wqkv = (const float*)d_in[4];
  const float* bqkv = (const float*)d_in[5];
  const float* Wo   = (const float*)d_in[6];
  const float* bo   = (const float*)d_in[7];
  const float* g2   = (const float*)d_in[8];
  const float* b2   = (const float*)d_in[9];
  const float* W1   = (const float*)d_in[10];
  const float* b1   = (const float*)d_in[11];
  const float* W2   = (const float*)d_in[12];
  const float* b2m  = (const float*)d_in[13];
  const float* g3   = (const float*)d_in[14];
  const float* b3   = (const float*)d_in[15];

  float* w  = (float*)d_ws;
  float* x  = w;               // [16384][64]  f32  (kept for residual)
  float* qf = w + 1048576;     // [4][4][4096][16] f32, pre-scaled by 0.25
  float* kf = w + 2097152;
  float* vf = w + 3145728;
  float* of = w + 4194304;     // attention out [16384][64]
  float* hf = w + 5242880;     // post-norm2 h
  float* tf = w + 1048576;     // relu hidden [16384][128] (aliases dead q,k)
  float* pf = w + 3145728;     // h + mlp     (aliases dead v)
  // total ws use: 6M floats = 24 MB

  dim3 g256(256), b256(256);
  // x = inputs @ Wp^T + bp
  gemm_k<128, 64, EPI_PLAIN><<<g256, b256, 0, stream>>>(inp, Wp, bp, x, nullptr, 1.f);
  // q,k,v = x @ Wqkv^T + bqkv, split + head-reshape; q pre-scaled 1/sqrt(16)
  gemm_k<64, 64, EPI_HEADS><<<g256, b256, 0, stream>>>(x, Wqkv,            bqkv,       qf, nullptr, 0.25f);
  gemm_k<64, 64, EPI_HEADS><<<g256, b256, 0, stream>>>(x, Wqkv + 64 * 64,  bqkv + 64,  kf, nullptr, 1.f);
  gemm_k<64, 64, EPI_HEADS><<<g256, b256, 0, stream>>>(x, Wqkv + 128 * 64, bqkv + 128, vf, nullptr, 1.f);
  // o = softmax(q k^T) v
  attn_k<<<g256, b256, 0, stream>>>(qf, kf, vf, of);
  // h = o @ Wo^T + bo + x ; batchnorm(g2,b2)
  gemm_k<64, 64, EPI_RESID><<<g256, b256, 0, stream>>>(of, Wo, bo, hf, x, 1.f);
  bn_k<<<g256, b256, 0, stream>>>(hf, g2, b2, hf, 0);
  // mlp: t = relu(h @ W1^T + b1); pre = t @ W2^T + b2m + h
  gemm_k<64, 128, EPI_RELU><<<g256, b256, 0, stream>>>(hf, W1, b1, tf, nullptr, 1.f);
  gemm_k<128, 64, EPI_RESID><<<g256, b256, 0, stream>>>(tf, W2, b2m, pf, hf, 1.f);
  // out = tanh(batchnorm(pre; g3,b3))
  bn_k<<<g256, b256, 0, stream>>>(pf, g3, b3, (float*)d_out, 1);
}

// Round 3
// 370.901 us; speedup vs baseline: 4.9681x; 4.9681x over previous
//
#include <hip/hip_runtime.h>
#include <hip/hip_bf16.h>

constexpr int NB = 4;      // batch
constexpr int NN = 4096;   // nodes
constexpr int CC = 64;     // channels
constexpr int NH = 4;      // heads
constexpr int DH = 16;     // head dim

enum { EPI_PLAIN = 0, EPI_HEADS = 1, EPI_RESID = 2, EPI_RELU = 3 };

// C[M][NC] = A[M][K] @ W[NC][K]^T + bias, with epilogue variants. All f32.
template<int K, int NC, int EPI>
__global__ __launch_bounds__(256) void gemm_k(
    const float* __restrict__ Ain,
    const float* __restrict__ W,
    const float* __restrict__ bias,
    float* __restrict__ out,
    const float* __restrict__ resid,
    float scale)
{
  constexpr int CPT = NC / 16;  // cols per thread (4, 8)
  __shared__ __align__(16) float As[64][68];
  __shared__ __align__(16) float Ws[64][NC + 4];

  const int tid = threadIdx.x;
  const int rowbase = blockIdx.x * 64;
  const int r4 = (tid & 15) * 4;
  const int cg = (tid >> 4) * CPT;

  float acc[4][CPT];
  #pragma unroll
  for (int i = 0; i < 4; ++i)
    #pragma unroll
    for (int j = 0; j < CPT; ++j) acc[i][j] = 0.f;

  for (int k0 = 0; k0 < K; k0 += 64) {
    if (k0) __syncthreads();
    #pragma unroll
    for (int i = 0; i < (NC * 64) / 256; ++i) {
      int idx = tid + i * 256;
      int c2 = idx >> 6, kk = idx & 63;
      Ws[kk][c2] = W[(size_t)c2 * K + k0 + kk];
    }
    #pragma unroll
    for (int i = 0; i < 16; ++i) {
      int idx = tid + i * 256;
      int r = idx >> 6, kk = idx & 63;
      As[kk][r] = Ain[(size_t)(rowbase + r) * K + k0 + kk];
    }
    __syncthreads();

    #pragma unroll 4
    for (int kk = 0; kk < 64; ++kk) {
      const float4 a = *(const float4*)&As[kk][r4];
      const float av[4] = {a.x, a.y, a.z, a.w};
      #pragma unroll
      for (int cj = 0; cj < CPT / 4; ++cj) {
        const float4 wv4 = *(const float4*)&Ws[kk][cg + cj * 4];
        const float wv[4] = {wv4.x, wv4.y, wv4.z, wv4.w};
        #pragma unroll
        for (int ri = 0; ri < 4; ++ri)
          #pragma unroll
          for (int ci = 0; ci < 4; ++ci)
            acc[ri][cj * 4 + ci] = fmaf(av[ri], wv[ci], acc[ri][cj * 4 + ci]);
      }
    }
  }

  float bi[CPT];
  #pragma unroll
  for (int j = 0; j < CPT; ++j) bi[j] = bias[cg + j];

  #pragma unroll
  for (int ri = 0; ri < 4; ++ri) {
    const int row = rowbase + r4 + ri;
    #pragma unroll
    for (int j = 0; j < CPT; ++j) {
      float v = acc[ri][j] + bi[j];
      const int c2 = cg + j;
      if constexpr (EPI == EPI_RELU) v = fmaxf(v, 0.f);
      if constexpr (EPI == EPI_RESID) v += resid[(size_t)row * NC + c2];
      if constexpr (EPI == EPI_HEADS) {
        v *= scale;
        const size_t oi =
            ((size_t)((row >> 12) * NH + (c2 >> 4)) * NN + (row & (NN - 1))) * DH + (c2 & (DH - 1));
        out[oi] = v;
      } else {
        out[(size_t)row * NC + c2] = v;
      }
    }
  }
}

// Block-tiled flash attention, f32 VALU. One block = one (b,h) x 64 query
// rows; K/V staged to LDS in 64-row chunks. Thread owns a 4(row)x4(col)
// S-tile and accumulates partial O over its 4 columns; cross-column-group
// reduction at the end via shuffles + LDS. No max-subtraction (scores are
// O(10); exp cannot overflow f32; result identical to softmax).
__global__ __launch_bounds__(256, 4) void attn_k(
    const float* __restrict__ qb, const float* __restrict__ kb,
    const float* __restrict__ vb, float* __restrict__ ob)
{
  // XCD-aware swizzle: xcd = bid & 7 (round-robin assumption, perf-only).
  // Each XCD owns 2 bh pairs -> K/V working set 2 MB, L2-resident.
  const int bid = blockIdx.x;
  const int j = bid >> 3;
  const int bh = 2 * (bid & 7) + (j >> 6);
  const int n0 = (j & 63) * 64;

  __shared__ __align__(16) float smem[4608];
  float (*Qs)[68] = (float(*)[68])smem;            // [16][68]
  float (*Ks)[68] = (float(*)[68])(smem + 1088);   // [16][68]
  float (*Vs)[20] = (float(*)[20])(smem + 2176);   // [64][20]
  // epilogue overlay (after a barrier): PO [4][64][16], RS [4][64]
  float* PO = smem;                                 // 4096 floats
  float* RS = smem + 4096;                          // 256 floats

  const int tid = threadIdx.x;
  const int r4 = (tid & 15) * 4;
  const int c4 = (tid >> 4) * 4;
  const int lane = tid & 63, wv = tid >> 6;

  const size_t bh_base = (size_t)bh * NN * DH;

  // stage Q tile (transpose to d-major), q pre-scaled by 0.25 upstream
  {
    const int r = tid >> 2, d4 = (tid & 3) * 4;
    const float4 qv = *(const float4*)(qb + bh_base + (size_t)(n0 + r) * DH + d4);
    Qs[d4 + 0][r] = qv.x; Qs[d4 + 1][r] = qv.y;
    Qs[d4 + 2][r] = qv.z; Qs[d4 + 3][r] = qv.w;
  }

  float po[4][16];
  #pragma unroll
  for (int ri = 0; ri < 4; ++ri)
    #pragma unroll
    for (int d = 0; d < 16; ++d) po[ri][d] = 0.f;
  float rs[4] = {0.f, 0.f, 0.f, 0.f};

  const int ldr = tid >> 2, ldd4 = (tid & 3) * 4;

  for (int c0 = 0; c0 < NN; c0 += 64) {
    __syncthreads();  // previous chunk's compute done before overwrite
    {
      const float4 kv = *(const float4*)(kb + bh_base + (size_t)(c0 + ldr) * DH + ldd4);
      const float4 vv = *(const float4*)(vb + bh_base + (size_t)(c0 + ldr) * DH + ldd4);
      Ks[ldd4 + 0][ldr] = kv.x; Ks[ldd4 + 1][ldr] = kv.y;
      Ks[ldd4 + 2][ldr] = kv.z; Ks[ldd4 + 3][ldr] = kv.w;
      *(float4*)&Vs[ldr][ldd4] = vv;
    }
    __syncthreads();

    // S-tile: s[ri][ci] = sum_d Q[r4+ri][d] * K[c4+ci][d]
    float s[4][4];
    #pragma unroll
    for (int ri = 0; ri < 4; ++ri)
      #pragma unroll
      for (int ci = 0; ci < 4; ++ci) s[ri][ci] = 0.f;
    #pragma unroll
    for (int d = 0; d < 16; ++d) {
      const float4 q4 = *(const float4*)&Qs[d][r4];
      const float4 k4 = *(const float4*)&Ks[d][c4];
      const float qv[4] = {q4.x, q4.y, q4.z, q4.w};
      const float kv[4] = {k4.x, k4.y, k4.z, k4.w};
      #pragma unroll
      for (int ri = 0; ri < 4; ++ri)
        #pragma unroll
        for (int ci = 0; ci < 4; ++ci)
          s[ri][ci] = fmaf(qv[ri], kv[ci], s[ri][ci]);
    }
    // exp + row-sum accumulation
    float p[4][4];
    #pragma unroll
    for (int ri = 0; ri < 4; ++ri)
      #pragma unroll
      for (int ci = 0; ci < 4; ++ci) {
        p[ri][ci] = __expf(s[ri][ci]);
        rs[ri] += p[ri][ci];
      }
    // PV: po[ri][d] += p[ri][ci] * V[c4+ci][d]
    #pragma unroll
    for (int ci = 0; ci < 4; ++ci) {
      #pragma unroll
      for (int d4i = 0; d4i < 4; ++d4i) {
        const float4 v4 = *(const float4*)&Vs[c4 + ci][d4i * 4];
        const float vv[4] = {v4.x, v4.y, v4.z, v4.w};
        #pragma unroll
        for (int ri = 0; ri < 4; ++ri)
          #pragma unroll
          for (int di = 0; di < 4; ++di)
            po[ri][d4i * 4 + di] = fmaf(p[ri][ci], vv[di], po[ri][d4i * 4 + di]);
      }
    }
  }

  // reduce rs/po across the 4 column-groups within each wave (lanes ^16, ^32)
  #pragma unroll
  for (int off = 16; off <= 32; off <<= 1) {
    #pragma unroll
    for (int ri = 0; ri < 4; ++ri) {
      rs[ri] += __shfl_xor(rs[ri], off);
      #pragma unroll
      for (int d = 0; d < 16; ++d)
        po[ri][d] += __shfl_xor(po[ri][d], off);
    }
  }
  __syncthreads();  // all waves done reading Ks/Vs; safe to overlay
  if (lane < 16) {
    #pragma unroll
    for (int ri = 0; ri < 4; ++ri) {
      const int r = lane * 4 + ri;
      RS[wv * 64 + r] = rs[ri];
      #pragma unroll
      for (int d = 0; d < 16; ++d)
        PO[(wv * 64 + r) * 16 + d] = po[ri][d];
    }
  }
  __syncthreads();
  // final: 1024 outputs, 4 per thread
  {
    const int r = tid & 63, d4 = (tid >> 6) * 4;
    const float inv = 1.f / (RS[r] + RS[64 + r] + RS[128 + r] + RS[192 + r]);
    float4 o;
    o.x = (PO[r * 16 + d4 + 0] + PO[(64 + r) * 16 + d4 + 0] +
           PO[(128 + r) * 16 + d4 + 0] + PO[(192 + r) * 16 + d4 + 0]) * inv;
    o.y = (PO[r * 16 + d4 + 1] + PO[(64 + r) * 16 + d4 + 1] +
           PO[(128 + r) * 16 + d4 + 1] + PO[(192 + r) * 16 + d4 + 1]) * inv;
    o.z = (PO[r * 16 + d4 + 2] + PO[(64 + r) * 16 + d4 + 2] +
           PO[(128 + r) * 16 + d4 + 2] + PO[(192 + r) * 16 + d4 + 2]) * inv;
    o.w = (PO[r * 16 + d4 + 3] + PO[(64 + r) * 16 + d4 + 3] +
           PO[(128 + r) * 16 + d4 + 3] + PO[(192 + r) * 16 + d4 + 3]) * inv;
    float* op = ob + ((size_t)(bh >> 2) * NN + n0 + r) * CC + (bh & 3) * DH + d4;
    *(float4*)op = o;
  }
}

// BatchNorm over the node axis per (b, c); biased var, EPS=1e-5.
__global__ __launch_bounds__(256) void bn_k(
    const float* __restrict__ in, const float* __restrict__ g,
    const float* __restrict__ b, float* __restrict__ out, int do_tanh)
{
  const int bb = blockIdx.x >> 6;
  const int c = blockIdx.x & 63;
  const float* base = in + (size_t)bb * NN * CC + c;
  float s = 0.f, sq = 0.f;
  #pragma unroll
  for (int i = 0; i < 16; ++i) {
    const float v = base[(size_t)(threadIdx.x + i * 256) * CC];
    s += v; sq += v * v;
  }
  #pragma unroll
  for (int off = 32; off; off >>= 1) {
    s += __shfl_down(s, off);
    sq += __shfl_down(sq, off);
  }
  __shared__ float red[8];
  const int wid = threadIdx.x >> 6;
  if ((threadIdx.x & 63) == 0) { red[wid] = s; red[wid + 4] = sq; }
  __syncthreads();
  const float ts = red[0] + red[1] + red[2] + red[3];
  const float tq = red[4] + red[5] + red[6] + red[7];
  const float mean = ts * (1.f / NN);
  const float var = tq * (1.f / NN) - mean * mean;
  const float rstd = rsqrtf(var + 1e-5f);
  const float scale = g[c] * rstd;
  const float shift = b[c] - mean * scale;
  float* ob = out + (size_t)bb * NN * CC + c;
  for (int i = 0; i < 16; ++i) {
    const size_t idx = (size_t)(threadIdx.x + i * 256) * CC;
    const float v = base[idx] * scale + shift;
    ob[idx] = do_tanh ? tanhf(v) : v;
  }
}

extern "C" void kernel_launch(void* const* d_in, const int* in_sizes, int n_in,
                              void* d_out, int out_size, void* d_ws, size_t ws_size,
                              hipStream_t stream)
{
  const float* inp  = (const float*)d_in[0];
  const float* Wp   = (const float*)d_in[2];
  const float* bp   = (const float*)d_in[3];
  const float* Wqkv = (const float*)d_in[4];
  const float* bqkv = (const float*)d_in[5];
  const float* Wo   = (const float*)d_in[6];
  const float* bo   = (const float*)d_in[7];
  const float* g2   = (const float*)d_in[8];
  const float* b2   = (const float*)d_in[9];
  const float* W1   = (const float*)d_in[10];
  const float* b1   = (const float*)d_in[11];
  const float* W2   = (const float*)d_in[12];
  const float* b2m  = (const float*)d_in[13];
  const float* g3   = (const float*)d_in[14];
  const float* b3   = (const float*)d_in[15];

  float* w  = (float*)d_ws;
  float* x  = w;               // [16384][64]
  float* qf = w + 1048576;     // [16][4096][16], pre-scaled 0.25
  float* kf = w + 2097152;
  float* vf = w + 3145728;
  float* of = w + 4194304;     // attention out [16384][64]
  float* hf = w + 5242880;     // post-norm2 h
  float* tf = w + 1048576;     // relu hidden (aliases dead q,k)
  float* pf = w + 3145728;     // h + mlp (aliases dead v)

  dim3 g256(256), b256(256);
  gemm_k<128, 64, EPI_PLAIN><<<g256, b256, 0, stream>>>(inp, Wp, bp, x, nullptr, 1.f);
  gemm_k<64, 64, EPI_HEADS><<<g256, b256, 0, stream>>>(x, Wqkv,            bqkv,       qf, nullptr, 0.25f);
  gemm_k<64, 64, EPI_HEADS><<<g256, b256, 0, stream>>>(x, Wqkv + 64 * 64,  bqkv + 64,  kf, nullptr, 1.f);
  gemm_k<64, 64, EPI_HEADS><<<g256, b256, 0, stream>>>(x, Wqkv + 128 * 64, bqkv + 128, vf, nullptr, 1.f);
  attn_k<<<dim3(1024), b256, 0, stream>>>(qf, kf, vf, of);
  gemm_k<64, 64, EPI_RESID><<<g256, b256, 0, stream>>>(of, Wo, bo, hf, x, 1.f);
  bn_k<<<g256, b256, 0, stream>>>(hf, g2, b2, hf, 0);
  gemm_k<64, 128, EPI_RELU><<<g256, b256, 0, stream>>>(hf, W1, b1, tf, nullptr, 1.f);
  gemm_k<128, 64, EPI_RESID><<<g256, b256, 0, stream>>>(tf, W2, b2m, pf, hf, 1.f);
  bn_k<<<g256, b256, 0, stream>>>(pf, g3, b3, (float*)d_out, 1);
}

// Round 4
// 220.861 us; speedup vs baseline: 8.3432x; 1.6793x over previous
//
#include <hip/hip_runtime.h>
#include <hip/hip_bf16.h>

constexpr int NB = 4;      // batch
constexpr int NN = 4096;   // nodes
constexpr int CC = 64;     // channels
constexpr int NH = 4;      // heads
constexpr int DH = 16;     // head dim

typedef _Float16 f16x4 __attribute__((ext_vector_type(4)));
typedef float f32x4 __attribute__((ext_vector_type(4)));

// exp(s) computed as exp2(s * log2e); fold 1/sqrt(Dh)=0.25 and log2e into q.
#define QSCALE 0.36067376022224085f  // 0.25 * log2(e)

enum { EPI_PLAIN = 0, EPI_QKV = 1, EPI_RESID = 2, EPI_RELU = 3 };

// C[M][NC] = A[M][K] @ W[NC][K]^T + bias, with epilogue variants. All f32 in.
// EPI_QKV: NC=192; writes q,k (f16, [bh][n][16], q pre-scaled QSCALE) and
// v transposed (f16, [bh][16][n]) into the f16 arena at `out`.
template<int K, int NC, int EPI>
__global__ __launch_bounds__(256) void gemm_k(
    const float* __restrict__ Ain,
    const float* __restrict__ W,
    const float* __restrict__ bias,
    float* __restrict__ out,
    const float* __restrict__ resid)
{
  constexpr int CPT = NC / 16;  // cols per thread (4, 8, 12)
  __shared__ __align__(16) float As[64][68];
  __shared__ __align__(16) float Ws[64][NC + 4];

  const int tid = threadIdx.x;
  const int rowbase = blockIdx.x * 64;
  const int r4 = (tid & 15) * 4;
  const int cg = (tid >> 4) * CPT;

  float acc[4][CPT];
  #pragma unroll
  for (int i = 0; i < 4; ++i)
    #pragma unroll
    for (int j = 0; j < CPT; ++j) acc[i][j] = 0.f;

  for (int k0 = 0; k0 < K; k0 += 64) {
    if (k0) __syncthreads();
    #pragma unroll
    for (int i = 0; i < (NC * 64) / 256; ++i) {
      int idx = tid + i * 256;
      int c2 = idx >> 6, kk = idx & 63;
      Ws[kk][c2] = W[(size_t)c2 * K + k0 + kk];
    }
    #pragma unroll
    for (int i = 0; i < 16; ++i) {
      int idx = tid + i * 256;
      int r = idx >> 6, kk = idx & 63;
      As[kk][r] = Ain[(size_t)(rowbase + r) * K + k0 + kk];
    }
    __syncthreads();

    #pragma unroll 4
    for (int kk = 0; kk < 64; ++kk) {
      const float4 a = *(const float4*)&As[kk][r4];
      const float av[4] = {a.x, a.y, a.z, a.w};
      #pragma unroll
      for (int cj = 0; cj < CPT / 4; ++cj) {
        const float4 wv4 = *(const float4*)&Ws[kk][cg + cj * 4];
        const float wv[4] = {wv4.x, wv4.y, wv4.z, wv4.w};
        #pragma unroll
        for (int ri = 0; ri < 4; ++ri)
          #pragma unroll
          for (int ci = 0; ci < 4; ++ci)
            acc[ri][cj * 4 + ci] = fmaf(av[ri], wv[ci], acc[ri][cj * 4 + ci]);
      }
    }
  }

  float bi[CPT];
  #pragma unroll
  for (int j = 0; j < CPT; ++j) bi[j] = bias[cg + j];

  #pragma unroll
  for (int ri = 0; ri < 4; ++ri) {
    const int row = rowbase + r4 + ri;
    #pragma unroll
    for (int j = 0; j < CPT; ++j) {
      float v = acc[ri][j] + bi[j];
      const int c2 = cg + j;
      if constexpr (EPI == EPI_RELU) v = fmaxf(v, 0.f);
      if constexpr (EPI == EPI_RESID) v += resid[(size_t)row * NC + c2];
      if constexpr (EPI == EPI_QKV) {
        const int which = c2 >> 6;         // 0=q 1=k 2=v
        const int hc = c2 & 63;
        const int bh = (row >> 12) * NH + (hc >> 4);
        const int d = hc & 15;
        const int n = row & (NN - 1);
        if (which == 0) v *= QSCALE;
        _Float16* f16b = (_Float16*)out;
        if (which < 2)
          f16b[(size_t)which * 1048576 + ((size_t)bh * NN + n) * DH + d] = (_Float16)v;
        else
          f16b[2097152 + ((size_t)bh * DH + d) * NN + n] = (_Float16)v;
      } else {
        out[(size_t)row * NC + c2] = v;
      }
    }
  }
}

// MFMA flash attention (f16 in / f32 acc). One wave = 32 q rows (2 fragments)
// of one (b,h); block = 4 waves = 128 rows; grid 512. No LDS, no barriers.
// Swapped QK: S^T = mfma(K_frag, Q_frag) so the exp'd output fragment IS the
// A-fragment for O = mfma(P, V) (layouts: A/B lane l holds row l&15,
// k=4*(l>>4)+e; D lane l holds col l&15, row=4*(l>>4)+reg). V is stored
// transposed so its B-fragment is one contiguous 8B load.
// No max-subtraction: scores O(5), exp2 in f32 cannot overflow; identical to
// softmax after normalization.
__global__ __launch_bounds__(256) void attn_k(
    const _Float16* __restrict__ qb, const _Float16* __restrict__ kb,
    const _Float16* __restrict__ vtb, float* __restrict__ ob)
{
  const int bid = blockIdx.x;           // 512 blocks
  const int j = bid >> 3;               // 0..63
  const int bh = 2 * (bid & 7) + (j >> 5);   // XCD-aware: 2 bh per XCD
  const int n0 = (j & 31) * 128;
  const int w = threadIdx.x >> 6;
  const int l = threadIdx.x & 63;
  const int g = l >> 4, i = l & 15;
  const int qbase = n0 + w * 32;

  const _Float16* __restrict__ qhp = qb + (size_t)bh * NN * DH;
  const _Float16* __restrict__ khp = kb + (size_t)bh * NN * DH;
  const _Float16* __restrict__ vhp = vtb + (size_t)bh * DH * NN;

  const f16x4 qfA = *(const f16x4*)(qhp + (size_t)(qbase + i) * DH + 4 * g);
  const f16x4 qfB = *(const f16x4*)(qhp + (size_t)(qbase + 16 + i) * DH + 4 * g);

  f32x4 oA = {0.f, 0.f, 0.f, 0.f}, oB = {0.f, 0.f, 0.f, 0.f};
  const f32x4 zz = {0.f, 0.f, 0.f, 0.f};
  float rsA = 0.f, rsB = 0.f;

  #pragma unroll 2
  for (int k0 = 0; k0 < NN; k0 += 16) {
    const f16x4 kf = *(const f16x4*)(khp + (size_t)(k0 + i) * DH + 4 * g);
    const f16x4 vf = *(const f16x4*)(vhp + (size_t)i * NN + k0 + 4 * g);
    f32x4 sA = __builtin_amdgcn_mfma_f32_16x16x16f16(kf, qfA, zz, 0, 0, 0);
    f32x4 sB = __builtin_amdgcn_mfma_f32_16x16x16f16(kf, qfB, zz, 0, 0, 0);
    const float a0 = exp2f(sA[0]), a1 = exp2f(sA[1]),
                a2 = exp2f(sA[2]), a3 = exp2f(sA[3]);
    const float b0 = exp2f(sB[0]), b1 = exp2f(sB[1]),
                b2 = exp2f(sB[2]), b3 = exp2f(sB[3]);
    rsA += (a0 + a1) + (a2 + a3);
    rsB += (b0 + b1) + (b2 + b3);
    f16x4 pA, pB;
    pA[0] = (_Float16)a0; pA[1] = (_Float16)a1;
    pA[2] = (_Float16)a2; pA[3] = (_Float16)a3;
    pB[0] = (_Float16)b0; pB[1] = (_Float16)b1;
    pB[2] = (_Float16)b2; pB[3] = (_Float16)b3;
    oA = __builtin_amdgcn_mfma_f32_16x16x16f16(pA, vf, oA, 0, 0, 0);
    oB = __builtin_amdgcn_mfma_f32_16x16x16f16(pB, vf, oB, 0, 0, 0);
  }

  // full row-sums: combine the 4 k-phase groups (lanes ^16, ^32)
  rsA += __shfl_xor(rsA, 16); rsA += __shfl_xor(rsA, 32);
  rsB += __shfl_xor(rsB, 16); rsB += __shfl_xor(rsB, 32);

  float* __restrict__ obase =
      ob + ((size_t)(bh >> 2) * NN) * CC + (size_t)(bh & 3) * DH + i;
  #pragma unroll
  for (int r = 0; r < 4; ++r) {
    const int ql = 4 * g + r;  // local row within 16-row tile
    const float ia = 1.f / __shfl(rsA, ql);
    const float ib = 1.f / __shfl(rsB, ql);
    obase[(size_t)(qbase + ql) * CC] = oA[r] * ia;
    obase[(size_t)(qbase + 16 + ql) * CC] = oB[r] * ib;
  }
}

// BatchNorm over the node axis per (b, c); biased var, EPS=1e-5.
__global__ __launch_bounds__(256) void bn_k(
    const float* __restrict__ in, const float* __restrict__ g,
    const float* __restrict__ b, float* __restrict__ out, int do_tanh)
{
  const int bb = blockIdx.x >> 6;
  const int c = blockIdx.x & 63;
  const float* base = in + (size_t)bb * NN * CC + c;
  float s = 0.f, sq = 0.f;
  #pragma unroll
  for (int i = 0; i < 16; ++i) {
    const float v = base[(size_t)(threadIdx.x + i * 256) * CC];
    s += v; sq += v * v;
  }
  #pragma unroll
  for (int off = 32; off; off >>= 1) {
    s += __shfl_down(s, off);
    sq += __shfl_down(sq, off);
  }
  __shared__ float red[8];
  const int wid = threadIdx.x >> 6;
  if ((threadIdx.x & 63) == 0) { red[wid] = s; red[wid + 4] = sq; }
  __syncthreads();
  const float ts = red[0] + red[1] + red[2] + red[3];
  const float tq = red[4] + red[5] + red[6] + red[7];
  const float mean = ts * (1.f / NN);
  const float var = tq * (1.f / NN) - mean * mean;
  const float rstd = rsqrtf(var + 1e-5f);
  const float scale = g[c] * rstd;
  const float shift = b[c] - mean * scale;
  float* ob = out + (size_t)bb * NN * CC + c;
  for (int i = 0; i < 16; ++i) {
    const size_t idx = (size_t)(threadIdx.x + i * 256) * CC;
    const float v = base[idx] * scale + shift;
    ob[idx] = do_tanh ? tanhf(v) : v;
  }
}

extern "C" void kernel_launch(void* const* d_in, const int* in_sizes, int n_in,
                              void* d_out, int out_size, void* d_ws, size_t ws_size,
                              hipStream_t stream)
{
  const float* inp  = (const float*)d_in[0];
  const float* Wp   = (const float*)d_in[2];
  const float* bp   = (const float*)d_in[3];
  const float* Wqkv = (const float*)d_in[4];
  const float* bqkv = (const float*)d_in[5];
  const float* Wo   = (const float*)d_in[6];
  const float* bo   = (const float*)d_in[7];
  const float* g2   = (const float*)d_in[8];
  const float* b2   = (const float*)d_in[9];
  const float* W1   = (const float*)d_in[10];
  const float* b1   = (const float*)d_in[11];
  const float* W2   = (const float*)d_in[12];
  const float* b2m  = (const float*)d_in[13];
  const float* g3   = (const float*)d_in[14];
  const float* b3   = (const float*)d_in[15];

  float* w = (float*)d_ws;
  // f32-element offsets into ws (total live extent 4.5M floats = 18 MB):
  float* x    = w;                 // [16384][64]        (dead after Wo GEMM)
  float* qkvA = w + 1048576;       // f16 arena: q 0..1M, k 1M..2M, vt 2M..3M
  float* of   = w + 2621440;       // attn out [16384][64] (dead after Wo GEMM)
  float* hf   = w + 3670016;       // post-norm2 h (live through mlp2)
  float* tf   = w;                 // relu hidden [16384][128] (over dead x/q/k)
  float* pf   = w + 2097152;       // h+mlp (over dead vt/of)

  const _Float16* qf16 = (const _Float16*)qkvA;

  dim3 g256(256), b256(256);
  gemm_k<128, 64, EPI_PLAIN><<<g256, b256, 0, stream>>>(inp, Wp, bp, x, nullptr);
  gemm_k<64, 192, EPI_QKV><<<g256, b256, 0, stream>>>(x, Wqkv, bqkv, qkvA, nullptr);
  attn_k<<<dim3(512), b256, 0, stream>>>(qf16, qf16 + 1048576, qf16 + 2097152, of);
  gemm_k<64, 64, EPI_RESID><<<g256, b256, 0, stream>>>(of, Wo, bo, hf, x);
  bn_k<<<g256, b256, 0, stream>>>(hf, g2, b2, hf, 0);
  gemm_k<64, 128, EPI_RELU><<<g256, b256, 0, stream>>>(hf, W1, b1, tf, nullptr);
  gemm_k<128, 64, EPI_RESID><<<g256, b256, 0, stream>>>(tf, W2, b2m, pf, hf);
  bn_k<<<g256, b256, 0, stream>>>(pf, g3, b3, (float*)d_out, 1);
}

// Round 5
// 178.690 us; speedup vs baseline: 10.3122x; 1.2360x over previous
//
#include <hip/hip_runtime.h>
#include <hip/hip_bf16.h>

constexpr int NB = 4;      // batch
constexpr int NN = 4096;   // nodes
constexpr int CC = 64;     // channels
constexpr int NH = 4;      // heads
constexpr int DH = 16;     // head dim
constexpr int KSPLIT = 4;  // attention K-dimension split (exact partial sums)

typedef _Float16 f16x4 __attribute__((ext_vector_type(4)));
typedef float f32x4 __attribute__((ext_vector_type(4)));

// exp(s) computed as exp2(s * log2e); fold 1/sqrt(Dh)=0.25 and log2e into q.
#define QSCALE 0.36067376022224085f  // 0.25 * log2(e)

enum { EPI_PLAIN = 0, EPI_QKV = 1, EPI_RESID = 2, EPI_RELU = 3 };

// C[M][NC] = A[M][K] @ W[NC][K]^T + bias, with epilogue variants. All f32 in.
// EPI_QKV: NC=192; writes q,k (f16, [bh][n][16], q pre-scaled QSCALE) and
// v transposed (f16, [bh][16][n]) into the f16 arena at `out`.
template<int K, int NC, int EPI>
__global__ __launch_bounds__(256) void gemm_k(
    const float* __restrict__ Ain,
    const float* __restrict__ W,
    const float* __restrict__ bias,
    float* __restrict__ out,
    const float* __restrict__ resid)
{
  constexpr int CPT = NC / 16;  // cols per thread (4, 8, 12)
  __shared__ __align__(16) float As[64][68];
  __shared__ __align__(16) float Ws[64][NC + 4];

  const int tid = threadIdx.x;
  const int rowbase = blockIdx.x * 64;
  const int r4 = (tid & 15) * 4;
  const int cg = (tid >> 4) * CPT;

  float acc[4][CPT];
  #pragma unroll
  for (int i = 0; i < 4; ++i)
    #pragma unroll
    for (int j = 0; j < CPT; ++j) acc[i][j] = 0.f;

  for (int k0 = 0; k0 < K; k0 += 64) {
    if (k0) __syncthreads();
    #pragma unroll
    for (int i = 0; i < (NC * 64) / 256; ++i) {
      int idx = tid + i * 256;
      int c2 = idx >> 6, kk = idx & 63;
      Ws[kk][c2] = W[(size_t)c2 * K + k0 + kk];
    }
    #pragma unroll
    for (int i = 0; i < 16; ++i) {
      int idx = tid + i * 256;
      int r = idx >> 6, kk = idx & 63;
      As[kk][r] = Ain[(size_t)(rowbase + r) * K + k0 + kk];
    }
    __syncthreads();

    #pragma unroll 4
    for (int kk = 0; kk < 64; ++kk) {
      const float4 a = *(const float4*)&As[kk][r4];
      const float av[4] = {a.x, a.y, a.z, a.w};
      #pragma unroll
      for (int cj = 0; cj < CPT / 4; ++cj) {
        const float4 wv4 = *(const float4*)&Ws[kk][cg + cj * 4];
        const float wv[4] = {wv4.x, wv4.y, wv4.z, wv4.w};
        #pragma unroll
        for (int ri = 0; ri < 4; ++ri)
          #pragma unroll
          for (int ci = 0; ci < 4; ++ci)
            acc[ri][cj * 4 + ci] = fmaf(av[ri], wv[ci], acc[ri][cj * 4 + ci]);
      }
    }
  }

  float bi[CPT];
  #pragma unroll
  for (int j = 0; j < CPT; ++j) bi[j] = bias[cg + j];

  #pragma unroll
  for (int ri = 0; ri < 4; ++ri) {
    const int row = rowbase + r4 + ri;
    #pragma unroll
    for (int j = 0; j < CPT; ++j) {
      float v = acc[ri][j] + bi[j];
      const int c2 = cg + j;
      if constexpr (EPI == EPI_RELU) v = fmaxf(v, 0.f);
      if constexpr (EPI == EPI_RESID) v += resid[(size_t)row * NC + c2];
      if constexpr (EPI == EPI_QKV) {
        const int which = c2 >> 6;         // 0=q 1=k 2=v
        const int hc = c2 & 63;
        const int bh = (row >> 12) * NH + (hc >> 4);
        const int d = hc & 15;
        const int n = row & (NN - 1);
        if (which == 0) v *= QSCALE;
        _Float16* f16b = (_Float16*)out;
        if (which < 2)
          f16b[(size_t)which * 1048576 + ((size_t)bh * NN + n) * DH + d] = (_Float16)v;
        else
          f16b[2097152 + ((size_t)bh * DH + d) * NN + n] = (_Float16)v;
      } else {
        out[(size_t)row * NC + c2] = v;
      }
    }
  }
}

// MFMA flash attention, K-split x4 (f16 in / f32 acc). One wave = 32 q rows
// (2 fragments) of one (b,h) over one K quarter-range; block = 4 waves; grid
// 2048 (8 waves/SIMD). No LDS, no barriers. Writes UNNORMALIZED partial O and
// partial rowsums; partials over disjoint K-ranges combine exactly by
// addition (no max-subtraction -> no rescaling), summed in red_k.
// Swapped QK: S^T = mfma(K_frag, Q_frag); exp'd fragment IS the A-fragment
// for O = mfma(P, V). V stored transposed so its B-fragment is one 8B load.
__global__ __launch_bounds__(256) void attn_k(
    const _Float16* __restrict__ qb, const _Float16* __restrict__ kb,
    const _Float16* __restrict__ vtb, float* __restrict__ po,
    float* __restrict__ rs)
{
  const int bid = blockIdx.x;            // 0..2047
  const int xcd = bid & 7;
  const int rest = bid >> 3;             // 0..255
  const int bh = 2 * xcd + (rest & 1);   // both bh of an XCD stay local
  const int ks = (rest >> 1) & 3;        // K-split index
  const int n0 = (rest >> 3) * 128;      // q-tile base (32 tiles)
  const int w = threadIdx.x >> 6;
  const int l = threadIdx.x & 63;
  const int g = l >> 4, i = l & 15;
  const int qbase = n0 + w * 32;
  const int kbeg = ks * (NN / KSPLIT);
  const int kend = kbeg + NN / KSPLIT;

  const _Float16* __restrict__ qhp = qb + (size_t)bh * NN * DH;
  const _Float16* __restrict__ khp = kb + (size_t)bh * NN * DH;
  const _Float16* __restrict__ vhp = vtb + (size_t)bh * DH * NN;

  const f16x4 qfA = *(const f16x4*)(qhp + (size_t)(qbase + i) * DH + 4 * g);
  const f16x4 qfB = *(const f16x4*)(qhp + (size_t)(qbase + 16 + i) * DH + 4 * g);

  f32x4 oA = {0.f, 0.f, 0.f, 0.f}, oB = {0.f, 0.f, 0.f, 0.f};
  const f32x4 zz = {0.f, 0.f, 0.f, 0.f};
  float rsA = 0.f, rsB = 0.f;

  #pragma unroll 2
  for (int k0 = kbeg; k0 < kend; k0 += 16) {
    const f16x4 kf = *(const f16x4*)(khp + (size_t)(k0 + i) * DH + 4 * g);
    const f16x4 vf = *(const f16x4*)(vhp + (size_t)i * NN + k0 + 4 * g);
    f32x4 sA = __builtin_amdgcn_mfma_f32_16x16x16f16(kf, qfA, zz, 0, 0, 0);
    f32x4 sB = __builtin_amdgcn_mfma_f32_16x16x16f16(kf, qfB, zz, 0, 0, 0);
    const float a0 = exp2f(sA[0]), a1 = exp2f(sA[1]),
                a2 = exp2f(sA[2]), a3 = exp2f(sA[3]);
    const float b0 = exp2f(sB[0]), b1 = exp2f(sB[1]),
                b2 = exp2f(sB[2]), b3 = exp2f(sB[3]);
    rsA += (a0 + a1) + (a2 + a3);
    rsB += (b0 + b1) + (b2 + b3);
    f16x4 pA, pB;
    pA[0] = (_Float16)a0; pA[1] = (_Float16)a1;
    pA[2] = (_Float16)a2; pA[3] = (_Float16)a3;
    pB[0] = (_Float16)b0; pB[1] = (_Float16)b1;
    pB[2] = (_Float16)b2; pB[3] = (_Float16)b3;
    oA = __builtin_amdgcn_mfma_f32_16x16x16f16(pA, vf, oA, 0, 0, 0);
    oB = __builtin_amdgcn_mfma_f32_16x16x16f16(pB, vf, oB, 0, 0, 0);
  }

  // full (partial-range) row-sums: combine the 4 k-phase groups
  rsA += __shfl_xor(rsA, 16); rsA += __shfl_xor(rsA, 32);
  rsB += __shfl_xor(rsB, 16); rsB += __shfl_xor(rsB, 32);

  // write partial O: po[ks][bh][n][16]
  float* __restrict__ pob = po + (size_t)(ks * 16 + bh) * NN * DH;
  #pragma unroll
  for (int r = 0; r < 4; ++r) {
    const int ql = 4 * g + r;
    pob[(size_t)(qbase + ql) * DH + i] = oA[r];
    pob[(size_t)(qbase + 16 + ql) * DH + i] = oB[r];
  }
  if (g == 0) {  // lanes 0..15 hold rowsums for rows qbase+i / qbase+16+i
    float* __restrict__ rsb = rs + (size_t)(ks * 16 + bh) * NN;
    rsb[qbase + i] = rsA;
    rsb[qbase + 16 + i] = rsB;
  }
}

// Combine K-split partials: of[b][n][h*16+d] = (sum_ks po) / (sum_ks rs).
__global__ __launch_bounds__(256) void red_k(
    const float* __restrict__ po, const float* __restrict__ rs,
    float* __restrict__ ob)
{
  const int t = blockIdx.x * 256 + threadIdx.x;  // 0..262143
  const int row = t >> 2;                        // bh*4096 + n
  const int d4 = (t & 3) * 4;
  const float inv = 1.f / (rs[row] + rs[65536 + row] +
                           rs[131072 + row] + rs[196608 + row]);
  const float4* p = (const float4*)(po + (size_t)row * DH + d4);
  // ks stride in float4 units: 16*4096*16/4 = 262144
  const float4 a = p[0], b = p[262144], c = p[524288], d = p[786432];
  float4 o;
  o.x = (a.x + b.x + c.x + d.x) * inv;
  o.y = (a.y + b.y + c.y + d.y) * inv;
  o.z = (a.z + b.z + c.z + d.z) * inv;
  o.w = (a.w + b.w + c.w + d.w) * inv;
  const int bh = row >> 12, n = row & (NN - 1);
  float* op = ob + ((size_t)(bh >> 2) * NN + n) * CC + (bh & 3) * DH + d4;
  *(float4*)op = o;
}

// BatchNorm over the node axis per (b, c); biased var, EPS=1e-5.
__global__ __launch_bounds__(256) void bn_k(
    const float* __restrict__ in, const float* __restrict__ g,
    const float* __restrict__ b, float* __restrict__ out, int do_tanh)
{
  const int bb = blockIdx.x >> 6;
  const int c = blockIdx.x & 63;
  const float* base = in + (size_t)bb * NN * CC + c;
  float s = 0.f, sq = 0.f;
  #pragma unroll
  for (int i = 0; i < 16; ++i) {
    const float v = base[(size_t)(threadIdx.x + i * 256) * CC];
    s += v; sq += v * v;
  }
  #pragma unroll
  for (int off = 32; off; off >>= 1) {
    s += __shfl_down(s, off);
    sq += __shfl_down(sq, off);
  }
  __shared__ float red[8];
  const int wid = threadIdx.x >> 6;
  if ((threadIdx.x & 63) == 0) { red[wid] = s; red[wid + 4] = sq; }
  __syncthreads();
  const float ts = red[0] + red[1] + red[2] + red[3];
  const float tq = red[4] + red[5] + red[6] + red[7];
  const float mean = ts * (1.f / NN);
  const float var = tq * (1.f / NN) - mean * mean;
  const float rstd = rsqrtf(var + 1e-5f);
  const float scale = g[c] * rstd;
  const float shift = b[c] - mean * scale;
  float* ob = out + (size_t)bb * NN * CC + c;
  for (int i = 0; i < 16; ++i) {
    const size_t idx = (size_t)(threadIdx.x + i * 256) * CC;
    const float v = base[idx] * scale + shift;
    ob[idx] = do_tanh ? tanhf(v) : v;
  }
}

extern "C" void kernel_launch(void* const* d_in, const int* in_sizes, int n_in,
                              void* d_out, int out_size, void* d_ws, size_t ws_size,
                              hipStream_t stream)
{
  const float* inp  = (const float*)d_in[0];
  const float* Wp   = (const float*)d_in[2];
  const float* bp   = (const float*)d_in[3];
  const float* Wqkv = (const float*)d_in[4];
  const float* bqkv = (const float*)d_in[5];
  const float* Wo   = (const float*)d_in[6];
  const float* bo   = (const float*)d_in[7];
  const float* g2   = (const float*)d_in[8];
  const float* b2   = (const float*)d_in[9];
  const float* W1   = (const float*)d_in[10];
  const float* b1   = (const float*)d_in[11];
  const float* W2   = (const float*)d_in[12];
  const float* b2m  = (const float*)d_in[13];
  const float* g3   = (const float*)d_in[14];
  const float* b3   = (const float*)d_in[15];

  float* w = (float*)d_ws;
  // f32-element offsets into ws (live extent ~9.2M floats = 37 MB):
  float* x    = w;                 // [16384][64]        (dead after Wo GEMM)
  float* qkvA = w + 1048576;       // f16 arena: q 0..1M, k 1M..2M, vt 2M..3M
  float* of   = w + 2621440;       // attn out [16384][64] (dead after Wo GEMM)
  float* hf   = w + 3670016;       // post-norm2 h (live through mlp2)
  float* poW  = w + 4718592;       // attn partial O [4][16][4096][16]
  float* rsW  = w + 8912896;       // attn partial rowsums [4][16][4096]
  float* tf   = w;                 // relu hidden [16384][128] (over dead x/q/k)
  float* pf   = w + 2097152;       // h+mlp (over dead vt/of)

  const _Float16* qf16 = (const _Float16*)qkvA;

  dim3 g256(256), b256(256);
  gemm_k<128, 64, EPI_PLAIN><<<g256, b256, 0, stream>>>(inp, Wp, bp, x, nullptr);
  gemm_k<64, 192, EPI_QKV><<<g256, b256, 0, stream>>>(x, Wqkv, bqkv, qkvA, nullptr);
  attn_k<<<dim3(2048), b256, 0, stream>>>(qf16, qf16 + 1048576, qf16 + 2097152,
                                          poW, rsW);
  red_k<<<dim3(1024), b256, 0, stream>>>(poW, rsW, of);
  gemm_k<64, 64, EPI_RESID><<<g256, b256, 0, stream>>>(of, Wo, bo, hf, x);
  bn_k<<<g256, b256, 0, stream>>>(hf, g2, b2, hf, 0);
  gemm_k<64, 128, EPI_RELU><<<g256, b256, 0, stream>>>(hf, W1, b1, tf, nullptr);
  gemm_k<128, 64, EPI_RESID><<<g256, b256, 0, stream>>>(tf, W2, b2m, pf, hf);
  bn_k<<<g256, b256, 0, stream>>>(pf, g3, b3, (float*)d_out, 1);
}

// Round 8
// 163.157 us; speedup vs baseline: 11.2940x; 1.0952x over previous
//
#include <hip/hip_runtime.h>
#include <hip/hip_bf16.h>

constexpr int NN = 4096;   // nodes
constexpr int CC = 64;     // channels
constexpr int NH = 4;      // heads
constexpr int DH = 16;     // head dim
constexpr int KSPLIT = 4;  // attention K-dimension split (exact partial sums)

typedef _Float16 f16x4 __attribute__((ext_vector_type(4)));
typedef float f32x4 __attribute__((ext_vector_type(4)));

// exp(s) = exp2(s*log2e); fold 1/sqrt(Dh)=0.25 and log2e into q.
#define QSCALE 0.36067376022224085f  // 0.25 * log2(e)
#define L2E2   2.8853900817779268f   // 2 * log2(e), for tanh

#if defined(__has_builtin)
#if __has_builtin(__builtin_amdgcn_exp2f)
#define FAST_EXP2(x) __builtin_amdgcn_exp2f(x)
#endif
#if __has_builtin(__builtin_amdgcn_rcpf)
#define FAST_RCP(x) __builtin_amdgcn_rcpf(x)
#endif
#endif
#ifndef FAST_EXP2
#define FAST_EXP2(x) exp2f(x)
#endif
#ifndef FAST_RCP
#define FAST_RCP(x) (1.0f / (x))
#endif

__device__ __forceinline__ float fast_tanh(float x) {
  // tanh(x) = 1 - 2/(exp(2x)+1); exact at +-inf, ~1e-7 abs err elsewhere
  const float t = FAST_EXP2(x * L2E2);
  return fmaf(-2.f, FAST_RCP(t + 1.f), 1.f);
}

// ---------------------------------------------------------------------------
// Fused project + QKV. Per 64-row block: x-tile = inp@Wp^T+bp (K=128), write
// x to global (residual), transpose x-tile into LDS, then qkv = x@Wqkv^T+bqkv
// (K=64, NC=192) with head-split epilogue: q,k f16 [bh][n][16] (q pre-scaled
// QSCALE), v transposed f16 [bh][16][n].
__global__ __launch_bounds__(256) void proj_qkv_k(
    const float* __restrict__ inp, const float* __restrict__ Wp,
    const float* __restrict__ bp, const float* __restrict__ Wqkv,
    const float* __restrict__ bqkv, float* __restrict__ xout,
    _Float16* __restrict__ f16b)
{
  __shared__ __align__(16) float As[64][68];
  __shared__ __align__(16) float Xs[64][68];     // phase A: Wp stage; then x^T
  __shared__ __align__(16) float W2s[64][196];

  const int tid = threadIdx.x;
  const int rowbase = blockIdx.x * 64;
  const int r4 = (tid & 15) * 4;
  const int cg = (tid >> 4) * 4;     // phase A cols
  const int cg2 = (tid >> 4) * 12;   // phase B cols

  // ---- phase A: x = inp @ Wp^T ----
  float acc[4][4];
  #pragma unroll
  for (int i = 0; i < 4; ++i)
    #pragma unroll
    for (int j = 0; j < 4; ++j) acc[i][j] = 0.f;

  for (int k0 = 0; k0 < 128; k0 += 64) {
    if (k0) __syncthreads();
    #pragma unroll
    for (int i = 0; i < 16; ++i) {
      int idx = tid + i * 256;
      int c2 = idx >> 6, kk = idx & 63;
      Xs[kk][c2] = Wp[(size_t)c2 * 128 + k0 + kk];
    }
    #pragma unroll
    for (int i = 0; i < 16; ++i) {
      int idx = tid + i * 256;
      int r = idx >> 6, kk = idx & 63;
      As[kk][r] = inp[(size_t)(rowbase + r) * 128 + k0 + kk];
    }
    __syncthreads();
    #pragma unroll 4
    for (int kk = 0; kk < 64; ++kk) {
      const float4 a = *(const float4*)&As[kk][r4];
      const float4 w4 = *(const float4*)&Xs[kk][cg];
      const float av[4] = {a.x, a.y, a.z, a.w};
      const float wv[4] = {w4.x, w4.y, w4.z, w4.w};
      #pragma unroll
      for (int ri = 0; ri < 4; ++ri)
        #pragma unroll
        for (int ci = 0; ci < 4; ++ci)
          acc[ri][ci] = fmaf(av[ri], wv[ci], acc[ri][ci]);
    }
  }

  float xv[4][4];
  #pragma unroll
  for (int ri = 0; ri < 4; ++ri)
    #pragma unroll
    for (int j = 0; j < 4; ++j) {
      xv[ri][j] = acc[ri][j] + bp[cg + j];
      xout[(size_t)(rowbase + r4 + ri) * CC + cg + j] = xv[ri][j];
    }

  __syncthreads();  // all phase-A LDS reads complete
  #pragma unroll
  for (int ri = 0; ri < 4; ++ri)
    #pragma unroll
    for (int j = 0; j < 4; ++j)
      Xs[cg + j][r4 + ri] = xv[ri][j];   // x^T (k-major for phase B)
  #pragma unroll
  for (int i = 0; i < 48; ++i) {
    int idx = tid + i * 256;
    int c2 = idx >> 6, kk = idx & 63;
    W2s[kk][c2] = Wqkv[(size_t)c2 * 64 + kk];
  }
  __syncthreads();

  // ---- phase B: qkv = x @ Wqkv^T ----
  float acc2[4][12];
  #pragma unroll
  for (int i = 0; i < 4; ++i)
    #pragma unroll
    for (int j = 0; j < 12; ++j) acc2[i][j] = 0.f;

  #pragma unroll 4
  for (int kk = 0; kk < 64; ++kk) {
    const float4 a = *(const float4*)&Xs[kk][r4];
    const float av[4] = {a.x, a.y, a.z, a.w};
    #pragma unroll
    for (int cj = 0; cj < 3; ++cj) {
      const float4 w4 = *(const float4*)&W2s[kk][cg2 + cj * 4];
      const float wv[4] = {w4.x, w4.y, w4.z, w4.w};
      #pragma unroll
      for (int ri = 0; ri < 4; ++ri)
        #pragma unroll
        for (int ci = 0; ci < 4; ++ci)
          acc2[ri][cj * 4 + ci] = fmaf(av[ri], wv[ci], acc2[ri][cj * 4 + ci]);
    }
  }

  #pragma unroll
  for (int ri = 0; ri < 4; ++ri) {
    const int row = rowbase + r4 + ri;
    const int n = row & (NN - 1);
    const int bq = (row >> 12) * NH;
    #pragma unroll
    for (int j = 0; j < 12; ++j) {
      float v = acc2[ri][j] + bqkv[cg2 + j];
      const int c2 = cg2 + j;
      const int which = c2 >> 6;         // 0=q 1=k 2=v
      const int hc = c2 & 63;
      const int bh = bq + (hc >> 4);
      const int d = hc & 15;
      if (which == 0) v *= QSCALE;
      if (which < 2)
        f16b[(size_t)which * 1048576 + ((size_t)bh * NN + n) * DH + d] = (_Float16)v;
      else
        f16b[2097152 + ((size_t)bh * DH + d) * NN + n] = (_Float16)v;
    }
  }
}

// ---------------------------------------------------------------------------
// MFMA flash attention, K-split x4 (f16 in / f32 acc). One wave = 32 q rows
// of one (b,h) over one K quarter; grid 2048 -> 8 waves/SIMD (VGPR capped 64
// via launch_bounds). Raw v_exp + packed f16 cvt. Writes UNNORMALIZED partial
// O and rowsums (disjoint K-ranges combine exactly by addition).
__global__ __launch_bounds__(256, 8) void attn_k(
    const _Float16* __restrict__ qb, const _Float16* __restrict__ kb,
    const _Float16* __restrict__ vtb, float* __restrict__ po,
    float* __restrict__ rs)
{
  const int bid = blockIdx.x;            // 0..2047
  const int xcd = bid & 7;
  const int rest = bid >> 3;             // 0..255
  const int bh = 2 * xcd + (rest & 1);   // both bh of an XCD stay local
  const int ks = (rest >> 1) & 3;        // K-split index
  const int n0 = (rest >> 3) * 128;      // q-tile base
  const int w = threadIdx.x >> 6;
  const int l = threadIdx.x & 63;
  const int g = l >> 4, i = l & 15;
  const int qbase = n0 + w * 32;
  const int kbeg = ks * (NN / KSPLIT);
  const int kend = kbeg + NN / KSPLIT;

  const _Float16* __restrict__ qhp = qb + (size_t)bh * NN * DH;
  const _Float16* __restrict__ khp = kb + (size_t)bh * NN * DH;
  const _Float16* __restrict__ vhp = vtb + (size_t)bh * DH * NN;

  const f16x4 qfA = *(const f16x4*)(qhp + (size_t)(qbase + i) * DH + 4 * g);
  const f16x4 qfB = *(const f16x4*)(qhp + (size_t)(qbase + 16 + i) * DH + 4 * g);

  f32x4 oA = {0.f, 0.f, 0.f, 0.f}, oB = {0.f, 0.f, 0.f, 0.f};
  const f32x4 zz = {0.f, 0.f, 0.f, 0.f};
  float rsA = 0.f, rsB = 0.f;

  #pragma unroll 2
  for (int k0 = kbeg; k0 < kend; k0 += 16) {
    const f16x4 kf = *(const f16x4*)(khp + (size_t)(k0 + i) * DH + 4 * g);
    const f16x4 vf = *(const f16x4*)(vhp + (size_t)i * NN + k0 + 4 * g);
    f32x4 sA = __builtin_amdgcn_mfma_f32_16x16x16f16(kf, qfA, zz, 0, 0, 0);
    f32x4 sB = __builtin_amdgcn_mfma_f32_16x16x16f16(kf, qfB, zz, 0, 0, 0);
    const float a0 = FAST_EXP2(sA[0]), a1 = FAST_EXP2(sA[1]),
                a2 = FAST_EXP2(sA[2]), a3 = FAST_EXP2(sA[3]);
    const float b0 = FAST_EXP2(sB[0]), b1 = FAST_EXP2(sB[1]),
                b2 = FAST_EXP2(sB[2]), b3 = FAST_EXP2(sB[3]);
    rsA += (a0 + a1) + (a2 + a3);
    rsB += (b0 + b1) + (b2 + b3);
    const auto alo = __builtin_amdgcn_cvt_pkrtz(a0, a1);  // __fp16 x2
    const auto ahi = __builtin_amdgcn_cvt_pkrtz(a2, a3);
    const auto blo = __builtin_amdgcn_cvt_pkrtz(b0, b1);
    const auto bhi = __builtin_amdgcn_cvt_pkrtz(b2, b3);
    f16x4 pA, pB;
    pA[0] = (_Float16)alo[0]; pA[1] = (_Float16)alo[1];
    pA[2] = (_Float16)ahi[0]; pA[3] = (_Float16)ahi[1];
    pB[0] = (_Float16)blo[0]; pB[1] = (_Float16)blo[1];
    pB[2] = (_Float16)bhi[0]; pB[3] = (_Float16)bhi[1];
    oA = __builtin_amdgcn_mfma_f32_16x16x16f16(pA, vf, oA, 0, 0, 0);
    oB = __builtin_amdgcn_mfma_f32_16x16x16f16(pB, vf, oB, 0, 0, 0);
  }

  rsA += __shfl_xor(rsA, 16); rsA += __shfl_xor(rsA, 32);
  rsB += __shfl_xor(rsB, 16); rsB += __shfl_xor(rsB, 32);

  float* __restrict__ pob = po + (size_t)(ks * 16 + bh) * NN * DH;
  #pragma unroll
  for (int r = 0; r < 4; ++r) {
    const int ql = 4 * g + r;
    pob[(size_t)(qbase + ql) * DH + i] = oA[r];
    pob[(size_t)(qbase + 16 + ql) * DH + i] = oB[r];
  }
  if (g == 0) {
    float* __restrict__ rsb = rs + (size_t)(ks * 16 + bh) * NN;
    rsb[qbase + i] = rsA;
    rsb[qbase + 16 + i] = rsB;
  }
}

// ---------------------------------------------------------------------------
// Wo GEMM with fused K-split reduction + residual. A[row][kk] is materialized
// in LDS staging directly from po/rs partials: of = (sum_ks po) / (sum_ks rs).
// pre2 = of @ Wo^T + bo + x.  po ks-stride = 16*4096*16 = 1048576 floats.
__global__ __launch_bounds__(256) void wo_red_k(
    const float* __restrict__ po, const float* __restrict__ rs,
    const float* __restrict__ Wo, const float* __restrict__ bo,
    const float* __restrict__ xin, float* __restrict__ out)
{
  __shared__ __align__(16) float As[64][68];
  __shared__ __align__(16) float Ws[64][68];
  __shared__ float Linv[64][4];

  const int tid = threadIdx.x;
  const int rowbase = blockIdx.x * 64;
  const int r4 = (tid & 15) * 4;
  const int cg = (tid >> 4) * 4;

  // per-(row, head) inverse denominators
  {
    const int r = tid & 63, hb = tid >> 6;
    const int row = rowbase + r;
    const int bh = (row >> 12) * NH + hb;
    const int n = row & (NN - 1);
    const float s = rs[(size_t)bh * NN + n] + rs[(size_t)(16 + bh) * NN + n] +
                    rs[(size_t)(32 + bh) * NN + n] + rs[(size_t)(48 + bh) * NN + n];
    Linv[r][hb] = 1.f / s;
  }
  // stage Wo
  #pragma unroll
  for (int i = 0; i < 16; ++i) {
    int idx = tid + i * 256;
    int c2 = idx >> 6, kk = idx & 63;
    Ws[kk][c2] = Wo[(size_t)c2 * 64 + kk];
  }
  __syncthreads();
  // stage A = reduced+normalized attention output
  #pragma unroll
  for (int i = 0; i < 16; ++i) {
    int idx = tid + i * 256;
    int r = idx >> 6, kk = idx & 63;
    const int row = rowbase + r;
    const int bh = (row >> 12) * NH + (kk >> 4);
    const int n = row & (NN - 1);
    const int d = kk & 15;
    const size_t base = (((size_t)bh * NN + n) * DH) + d;
    const float v = po[base] + po[base + 1048576] +
                    po[base + 2097152] + po[base + 3145728];
    As[kk][r] = v * Linv[r][kk >> 4];
  }
  __syncthreads();

  float acc[4][4];
  #pragma unroll
  for (int i = 0; i < 4; ++i)
    #pragma unroll
    for (int j = 0; j < 4; ++j) acc[i][j] = 0.f;

  #pragma unroll 4
  for (int kk = 0; kk < 64; ++kk) {
    const float4 a = *(const float4*)&As[kk][r4];
    const float4 w4 = *(const float4*)&Ws[kk][cg];
    const float av[4] = {a.x, a.y, a.z, a.w};
    const float wv[4] = {w4.x, w4.y, w4.z, w4.w};
    #pragma unroll
    for (int ri = 0; ri < 4; ++ri)
      #pragma unroll
      for (int ci = 0; ci < 4; ++ci)
        acc[ri][ci] = fmaf(av[ri], wv[ci], acc[ri][ci]);
  }

  #pragma unroll
  for (int ri = 0; ri < 4; ++ri) {
    const int row = rowbase + r4 + ri;
    #pragma unroll
    for (int j = 0; j < 4; ++j) {
      const int c = cg + j;
      out[(size_t)row * CC + c] =
          acc[ri][j] + bo[c] + xin[(size_t)row * CC + c];
    }
  }
}

// ---------------------------------------------------------------------------
// Fused MLP: t = relu(h @ W1^T + b1) (kept in LDS), pre3 = t @ W2^T + b2m + h.
__global__ __launch_bounds__(256) void mlp_k(
    const float* __restrict__ hf, const float* __restrict__ W1,
    const float* __restrict__ b1, const float* __restrict__ W2,
    const float* __restrict__ b2m, float* __restrict__ out)
{
  __shared__ __align__(16) float As[64][68];     // h^T tile (k-major)
  __shared__ __align__(16) float Wbuf[8704];     // W1 [64][132] then W2 [128][68]
  __shared__ __align__(16) float Ts[128][68];    // relu(t)^T

  const int tid = threadIdx.x;
  const int rowbase = blockIdx.x * 64;
  const int r4 = (tid & 15) * 4;
  const int cg8 = (tid >> 4) * 8;    // phase 1 cols (128/16)
  const int cg4 = (tid >> 4) * 4;    // phase 2 cols (64/16)

  // stage h tile + W1
  #pragma unroll
  for (int i = 0; i < 32; ++i) {
    int idx = tid + i * 256;          // 8192 = 128c x 64k
    int c2 = idx >> 6, kk = idx & 63;
    Wbuf[kk * 132 + c2] = W1[(size_t)c2 * 64 + kk];
  }
  #pragma unroll
  for (int i = 0; i < 16; ++i) {
    int idx = tid + i * 256;
    int r = idx >> 6, kk = idx & 63;
    As[kk][r] = hf[(size_t)(rowbase + r) * CC + kk];
  }
  __syncthreads();

  // phase 1: t = relu(h @ W1^T + b1)
  float acc1[4][8];
  #pragma unroll
  for (int i = 0; i < 4; ++i)
    #pragma unroll
    for (int j = 0; j < 8; ++j) acc1[i][j] = 0.f;

  #pragma unroll 4
  for (int kk = 0; kk < 64; ++kk) {
    const float4 a = *(const float4*)&As[kk][r4];
    const float av[4] = {a.x, a.y, a.z, a.w};
    #pragma unroll
    for (int cj = 0; cj < 2; ++cj) {
      const float4 w4 = *(const float4*)&Wbuf[kk * 132 + cg8 + cj * 4];
      const float wv[4] = {w4.x, w4.y, w4.z, w4.w};
      #pragma unroll
      for (int ri = 0; ri < 4; ++ri)
        #pragma unroll
        for (int ci = 0; ci < 4; ++ci)
          acc1[ri][cj * 4 + ci] = fmaf(av[ri], wv[ci], acc1[ri][cj * 4 + ci]);
    }
  }
  #pragma unroll
  for (int ri = 0; ri < 4; ++ri)
    #pragma unroll
    for (int j = 0; j < 8; ++j)
      Ts[cg8 + j][r4 + ri] = fmaxf(acc1[ri][j] + b1[cg8 + j], 0.f);
  __syncthreads();

  // stage W2 over W1
  #pragma unroll
  for (int i = 0; i < 32; ++i) {
    int idx = tid + i * 256;          // 8192 = 64c x 128k
    int c2 = idx >> 7, kk = idx & 127;
    Wbuf[kk * 68 + c2] = W2[(size_t)c2 * 128 + kk];
  }
  __syncthreads();

  // phase 2: pre3 = t @ W2^T + b2m + h
  float acc2[4][4];
  #pragma unroll
  for (int i = 0; i < 4; ++i)
    #pragma unroll
    for (int j = 0; j < 4; ++j) acc2[i][j] = 0.f;

  #pragma unroll 4
  for (int kk = 0; kk < 128; ++kk) {
    const float4 a = *(const float4*)&Ts[kk][r4];
    const float4 w4 = *(const float4*)&Wbuf[kk * 68 + cg4];
    const float av[4] = {a.x, a.y, a.z, a.w};
    const float wv[4] = {w4.x, w4.y, w4.z, w4.w};
    #pragma unroll
    for (int ri = 0; ri < 4; ++ri)
      #pragma unroll
      for (int ci = 0; ci < 4; ++ci)
        acc2[ri][ci] = fmaf(av[ri], wv[ci], acc2[ri][ci]);
  }

  #pragma unroll
  for (int ri = 0; ri < 4; ++ri) {
    const int row = rowbase + r4 + ri;
    #pragma unroll
    for (int j = 0; j < 4; ++j) {
      const int c = cg4 + j;
      out[(size_t)row * CC + c] = acc2[ri][j] + b2m[c] + As[c][r4 + ri];
    }
  }
}

// ---------------------------------------------------------------------------
// BatchNorm over node axis, 4 channels per block (float4), biased var,
// EPS=1e-5, optional fused tanh. Grid 64 = 4 b x 16 channel-quads.
// In-place safe (each thread rewrites only elements it re-reads itself).
__global__ __launch_bounds__(256) void bn4_k(
    const float* __restrict__ in, const float* __restrict__ g,
    const float* __restrict__ b, float* __restrict__ out, int do_tanh)
{
  const int bb = blockIdx.x >> 4;
  const int c4 = (blockIdx.x & 15) * 4;
  const float* __restrict__ base = in + (size_t)bb * NN * CC + c4;
  const int tid = threadIdx.x;

  float4 s = {0, 0, 0, 0}, sq = {0, 0, 0, 0};
  #pragma unroll
  for (int i = 0; i < 16; ++i) {
    const float4 v = *(const float4*)&base[(size_t)(tid + i * 256) * CC];
    s.x += v.x; s.y += v.y; s.z += v.z; s.w += v.w;
    sq.x = fmaf(v.x, v.x, sq.x); sq.y = fmaf(v.y, v.y, sq.y);
    sq.z = fmaf(v.z, v.z, sq.z); sq.w = fmaf(v.w, v.w, sq.w);
  }
  #pragma unroll
  for (int off = 32; off; off >>= 1) {
    s.x += __shfl_down(s.x, off); s.y += __shfl_down(s.y, off);
    s.z += __shfl_down(s.z, off); s.w += __shfl_down(s.w, off);
    sq.x += __shfl_down(sq.x, off); sq.y += __shfl_down(sq.y, off);
    sq.z += __shfl_down(sq.z, off); sq.w += __shfl_down(sq.w, off);
  }
  __shared__ float red[4][8];
  const int wv = tid >> 6;
  if ((tid & 63) == 0) {
    red[wv][0] = s.x; red[wv][1] = s.y; red[wv][2] = s.z; red[wv][3] = s.w;
    red[wv][4] = sq.x; red[wv][5] = sq.y; red[wv][6] = sq.z; red[wv][7] = sq.w;
  }
  __syncthreads();
  float scale[4], shift[4];
  #pragma unroll
  for (int j = 0; j < 4; ++j) {
    const float ts = red[0][j] + red[1][j] + red[2][j] + red[3][j];
    const float tq = red[0][4 + j] + red[1][4 + j] + red[2][4 + j] + red[3][4 + j];
    const float mean = ts * (1.f / NN);
    const float var = tq * (1.f / NN) - mean * mean;
    const float rstd = rsqrtf(var + 1e-5f);
    scale[j] = g[c4 + j] * rstd;
    shift[j] = b[c4 + j] - mean * scale[j];
  }
  float* __restrict__ ob = out + (size_t)bb * NN * CC + c4;
  #pragma unroll
  for (int i = 0; i < 16; ++i) {
    const size_t idx = (size_t)(tid + i * 256) * CC;
    const float4 v = *(const float4*)&base[idx];
    float4 o;
    o.x = v.x * scale[0] + shift[0];
    o.y = v.y * scale[1] + shift[1];
    o.z = v.z * scale[2] + shift[2];
    o.w = v.w * scale[3] + shift[3];
    if (do_tanh) {
      o.x = fast_tanh(o.x); o.y = fast_tanh(o.y);
      o.z = fast_tanh(o.z); o.w = fast_tanh(o.w);
    }
    *(float4*)&ob[idx] = o;
  }
}

// ---------------------------------------------------------------------------
extern "C" void kernel_launch(void* const* d_in, const int* in_sizes, int n_in,
                              void* d_out, int out_size, void* d_ws, size_t ws_size,
                              hipStream_t stream)
{
  const float* inp  = (const float*)d_in[0];
  const float* Wp   = (const float*)d_in[2];
  const float* bp   = (const float*)d_in[3];
  const float* Wqkv = (const float*)d_in[4];
  const float* bqkv = (const float*)d_in[5];
  const float* Wo   = (const float*)d_in[6];
  const float* bo   = (const float*)d_in[7];
  const float* g2   = (const float*)d_in[8];
  const float* b2   = (const float*)d_in[9];
  const float* W1   = (const float*)d_in[10];
  const float* b1   = (const float*)d_in[11];
  const float* W2   = (const float*)d_in[12];
  const float* b2m  = (const float*)d_in[13];
  const float* g3   = (const float*)d_in[14];
  const float* b3   = (const float*)d_in[15];

  float* w = (float*)d_ws;
  float* x    = w;                 // [16384][64]   (dead after wo_red)
  float* qkvA = w + 1048576;       // f16 arena: q 0..1M, k 1M..2M, vt 2M..3M halves
  float* hf   = w + 2621440;       // pre2 -> (in-place bn) h
  float* pf   = w + 3670016;       // pre3 = h + mlp
  float* poW  = w + 4718592;       // attn partial O [4][16][4096][16]
  float* rsW  = w + 8912896;       // attn partial rowsums [4][16][4096]

  _Float16* f16b = (_Float16*)qkvA;

  proj_qkv_k<<<dim3(256), dim3(256), 0, stream>>>(inp, Wp, bp, Wqkv, bqkv, x, f16b);
  attn_k<<<dim3(2048), dim3(256), 0, stream>>>(f16b, f16b + 1048576,
                                               f16b + 2097152, poW, rsW);
  wo_red_k<<<dim3(256), dim3(256), 0, stream>>>(poW, rsW, Wo, bo, x, hf);
  bn4_k<<<dim3(64), dim3(256), 0, stream>>>(hf, g2, b2, hf, 0);
  mlp_k<<<dim3(256), dim3(256), 0, stream>>>(hf, W1, b1, W2, b2m, pf);
  bn4_k<<<dim3(64), dim3(256), 0, stream>>>(pf, g3, b3, (float*)d_out, 1);
}

// Round 10
// 127.858 us; speedup vs baseline: 14.4120x; 1.2761x over previous
//
#include <hip/hip_runtime.h>
#include <hip/hip_bf16.h>

constexpr int NN = 4096;   // nodes
constexpr int CC = 64;     // channels
constexpr int NH = 4;      // heads
constexpr int DH = 16;     // head dim
constexpr int KSPLIT = 4;  // attention K-dimension split (exact partial sums)

typedef _Float16 f16x4 __attribute__((ext_vector_type(4)));
typedef float f32x4 __attribute__((ext_vector_type(4)));

// exp(s) = exp2(s*log2e); fold 1/sqrt(Dh)=0.25 and log2e into q.
#define QSCALE 0.36067376022224085f  // 0.25 * log2(e)
#define L2E2   2.8853900817779268f   // 2 * log2(e), for tanh

#if defined(__has_builtin)
#if __has_builtin(__builtin_amdgcn_exp2f)
#define FAST_EXP2(x) __builtin_amdgcn_exp2f(x)
#endif
#if __has_builtin(__builtin_amdgcn_rcpf)
#define FAST_RCP(x) __builtin_amdgcn_rcpf(x)
#endif
#endif
#ifndef FAST_EXP2
#define FAST_EXP2(x) exp2f(x)
#endif
#ifndef FAST_RCP
#define FAST_RCP(x) (1.0f / (x))
#endif

__device__ __forceinline__ float fast_tanh(float x) {
  // tanh(x) = 1 - 2/(exp(2x)+1); exact at +-inf, ~1e-7 abs err elsewhere
  const float t = FAST_EXP2(x * L2E2);
  return fmaf(-2.f, FAST_RCP(t + 1.f), 1.f);
}

// ---------------------------------------------------------------------------
// Fused project + QKV. Per 64-row block: x-tile = inp@Wp^T+bp (K=128), write
// x to global (residual), transpose x-tile into LDS, then qkv = x@Wqkv^T+bqkv
// (K=64, NC=192) with head-split epilogue: q,k f16 [bh][n][16] (q pre-scaled
// QSCALE), v transposed f16 [bh][16][n].
__global__ __launch_bounds__(256) void proj_qkv_k(
    const float* __restrict__ inp, const float* __restrict__ Wp,
    const float* __restrict__ bp, const float* __restrict__ Wqkv,
    const float* __restrict__ bqkv, float* __restrict__ xout,
    _Float16* __restrict__ f16b)
{
  __shared__ __align__(16) float As[64][68];
  __shared__ __align__(16) float Xs[64][68];     // phase A: Wp stage; then x^T
  __shared__ __align__(16) float W2s[64][196];

  const int tid = threadIdx.x;
  const int rowbase = blockIdx.x * 64;
  const int r4 = (tid & 15) * 4;
  const int cg = (tid >> 4) * 4;     // phase A cols
  const int cg2 = (tid >> 4) * 12;   // phase B cols

  // ---- phase A: x = inp @ Wp^T ----
  float acc[4][4];
  #pragma unroll
  for (int i = 0; i < 4; ++i)
    #pragma unroll
    for (int j = 0; j < 4; ++j) acc[i][j] = 0.f;

  for (int k0 = 0; k0 < 128; k0 += 64) {
    if (k0) __syncthreads();
    #pragma unroll
    for (int i = 0; i < 16; ++i) {
      int idx = tid + i * 256;
      int c2 = idx >> 6, kk = idx & 63;
      Xs[kk][c2] = Wp[(size_t)c2 * 128 + k0 + kk];
    }
    #pragma unroll
    for (int i = 0; i < 16; ++i) {
      int idx = tid + i * 256;
      int r = idx >> 6, kk = idx & 63;
      As[kk][r] = inp[(size_t)(rowbase + r) * 128 + k0 + kk];
    }
    __syncthreads();
    #pragma unroll 4
    for (int kk = 0; kk < 64; ++kk) {
      const float4 a = *(const float4*)&As[kk][r4];
      const float4 w4 = *(const float4*)&Xs[kk][cg];
      const float av[4] = {a.x, a.y, a.z, a.w};
      const float wv[4] = {w4.x, w4.y, w4.z, w4.w};
      #pragma unroll
      for (int ri = 0; ri < 4; ++ri)
        #pragma unroll
        for (int ci = 0; ci < 4; ++ci)
          acc[ri][ci] = fmaf(av[ri], wv[ci], acc[ri][ci]);
    }
  }

  float xv[4][4];
  #pragma unroll
  for (int ri = 0; ri < 4; ++ri)
    #pragma unroll
    for (int j = 0; j < 4; ++j) {
      xv[ri][j] = acc[ri][j] + bp[cg + j];
      xout[(size_t)(rowbase + r4 + ri) * CC + cg + j] = xv[ri][j];
    }

  __syncthreads();  // all phase-A LDS reads complete
  #pragma unroll
  for (int ri = 0; ri < 4; ++ri)
    #pragma unroll
    for (int j = 0; j < 4; ++j)
      Xs[cg + j][r4 + ri] = xv[ri][j];   // x^T (k-major for phase B)
  #pragma unroll
  for (int i = 0; i < 48; ++i) {
    int idx = tid + i * 256;
    int c2 = idx >> 6, kk = idx & 63;
    W2s[kk][c2] = Wqkv[(size_t)c2 * 64 + kk];
  }
  __syncthreads();

  // ---- phase B: qkv = x @ Wqkv^T ----
  float acc2[4][12];
  #pragma unroll
  for (int i = 0; i < 4; ++i)
    #pragma unroll
    for (int j = 0; j < 12; ++j) acc2[i][j] = 0.f;

  #pragma unroll 4
  for (int kk = 0; kk < 64; ++kk) {
    const float4 a = *(const float4*)&Xs[kk][r4];
    const float av[4] = {a.x, a.y, a.z, a.w};
    #pragma unroll
    for (int cj = 0; cj < 3; ++cj) {
      const float4 w4 = *(const float4*)&W2s[kk][cg2 + cj * 4];
      const float wv[4] = {w4.x, w4.y, w4.z, w4.w};
      #pragma unroll
      for (int ri = 0; ri < 4; ++ri)
        #pragma unroll
        for (int ci = 0; ci < 4; ++ci)
          acc2[ri][cj * 4 + ci] = fmaf(av[ri], wv[ci], acc2[ri][cj * 4 + ci]);
    }
  }

  #pragma unroll
  for (int ri = 0; ri < 4; ++ri) {
    const int row = rowbase + r4 + ri;
    const int n = row & (NN - 1);
    const int bq = (row >> 12) * NH;
    #pragma unroll
    for (int j = 0; j < 12; ++j) {
      float v = acc2[ri][j] + bqkv[cg2 + j];
      const int c2 = cg2 + j;
      const int which = c2 >> 6;         // 0=q 1=k 2=v
      const int hc = c2 & 63;
      const int bh = bq + (hc >> 4);
      const int d = hc & 15;
      if (which == 0) v *= QSCALE;
      if (which < 2)
        f16b[(size_t)which * 1048576 + ((size_t)bh * NN + n) * DH + d] = (_Float16)v;
      else
        f16b[2097152 + ((size_t)bh * DH + d) * NN + n] = (_Float16)v;
    }
  }
}

// ---------------------------------------------------------------------------
// MFMA flash attention, K-split x4 (f16 in / f32 acc), LDS-staged K/V.
// Block = 4 waves, all same (bh, ks): K and V chunks (64 rows) are staged
// once per block via coalesced loads (V's transposed-global layout is a
// 16-way scatter if read per-fragment -> staging cuts L2 requests ~16x).
// One wave = 32 q rows; grid 2048 -> 8 blocks/CU. Writes UNNORMALIZED
// partial O and rowsums (disjoint K-ranges combine exactly by addition).
__global__ __launch_bounds__(256, 8) void attn_k(
    const _Float16* __restrict__ qb, const _Float16* __restrict__ kb,
    const _Float16* __restrict__ vtb, float* __restrict__ po,
    float* __restrict__ rs)
{
  __shared__ _Float16 Kl[64][20];   // [k-row][d], row 40B (8B-aligned reads)
  __shared__ _Float16 Vl[16][72];   // [d][k-col], row 144B

  const int bid = blockIdx.x;            // 0..2047
  const int xcd = bid & 7;
  const int rest = bid >> 3;             // 0..255
  const int bh = 2 * xcd + (rest & 1);   // both bh of an XCD stay local
  const int ks = (rest >> 1) & 3;        // K-split index
  const int n0 = (rest >> 3) * 128;      // q-tile base
  const int tid = threadIdx.x;
  const int w = tid >> 6;
  const int l = tid & 63;
  const int g = l >> 4, i = l & 15;
  const int qbase = n0 + w * 32;
  const int kbeg = ks * (NN / KSPLIT);
  const int kend = kbeg + NN / KSPLIT;

  const _Float16* __restrict__ qhp = qb + (size_t)bh * NN * DH;
  const _Float16* __restrict__ khp = kb + (size_t)bh * NN * DH;
  const _Float16* __restrict__ vhp = vtb + (size_t)bh * DH * NN;

  const f16x4 qfA = *(const f16x4*)(qhp + (size_t)(qbase + i) * DH + 4 * g);
  const f16x4 qfB = *(const f16x4*)(qhp + (size_t)(qbase + 16 + i) * DH + 4 * g);

  f32x4 oA = {0.f, 0.f, 0.f, 0.f}, oB = {0.f, 0.f, 0.f, 0.f};
  const f32x4 zz = {0.f, 0.f, 0.f, 0.f};
  float rsA = 0.f, rsB = 0.f;

  const int srow = tid >> 2, spart = tid & 3;       // K staging map
  const int sd = tid >> 4, scol = (tid & 15) * 4;   // V staging map

  for (int c0 = kbeg; c0 < kend; c0 += 64) {
    __syncthreads();  // previous chunk's compute done before overwrite
    *(f16x4*)&Kl[srow][spart * 4] =
        *(const f16x4*)(khp + (size_t)(c0 + srow) * DH + spart * 4);
    *(f16x4*)&Vl[sd][scol] =
        *(const f16x4*)(vhp + (size_t)sd * NN + c0 + scol);
    __syncthreads();

    #pragma unroll
    for (int kk = 0; kk < 64; kk += 16) {
      const f16x4 kf = *(const f16x4*)&Kl[kk + i][4 * g];
      const f16x4 vf = *(const f16x4*)&Vl[i][kk + 4 * g];
      f32x4 sA = __builtin_amdgcn_mfma_f32_16x16x16f16(kf, qfA, zz, 0, 0, 0);
      f32x4 sB = __builtin_amdgcn_mfma_f32_16x16x16f16(kf, qfB, zz, 0, 0, 0);
      const float a0 = FAST_EXP2(sA[0]), a1 = FAST_EXP2(sA[1]),
                  a2 = FAST_EXP2(sA[2]), a3 = FAST_EXP2(sA[3]);
      const float b0 = FAST_EXP2(sB[0]), b1 = FAST_EXP2(sB[1]),
                  b2 = FAST_EXP2(sB[2]), b3 = FAST_EXP2(sB[3]);
      rsA += (a0 + a1) + (a2 + a3);
      rsB += (b0 + b1) + (b2 + b3);
      const auto alo = __builtin_amdgcn_cvt_pkrtz(a0, a1);  // __fp16 x2
      const auto ahi = __builtin_amdgcn_cvt_pkrtz(a2, a3);
      const auto blo = __builtin_amdgcn_cvt_pkrtz(b0, b1);
      const auto bhi = __builtin_amdgcn_cvt_pkrtz(b2, b3);
      f16x4 pA, pB;
      pA[0] = (_Float16)alo[0]; pA[1] = (_Float16)alo[1];
      pA[2] = (_Float16)ahi[0]; pA[3] = (_Float16)ahi[1];
      pB[0] = (_Float16)blo[0]; pB[1] = (_Float16)blo[1];
      pB[2] = (_Float16)bhi[0]; pB[3] = (_Float16)bhi[1];
      oA = __builtin_amdgcn_mfma_f32_16x16x16f16(pA, vf, oA, 0, 0, 0);
      oB = __builtin_amdgcn_mfma_f32_16x16x16f16(pB, vf, oB, 0, 0, 0);
    }
  }

  rsA += __shfl_xor(rsA, 16); rsA += __shfl_xor(rsA, 32);
  rsB += __shfl_xor(rsB, 16); rsB += __shfl_xor(rsB, 32);

  float* __restrict__ pob = po + (size_t)(ks * 16 + bh) * NN * DH;
  #pragma unroll
  for (int r = 0; r < 4; ++r) {
    const int ql = 4 * g + r;
    pob[(size_t)(qbase + ql) * DH + i] = oA[r];
    pob[(size_t)(qbase + 16 + ql) * DH + i] = oB[r];
  }
  if (g == 0) {
    float* __restrict__ rsb = rs + (size_t)(ks * 16 + bh) * NN;
    rsb[qbase + i] = rsA;
    rsb[qbase + 16 + i] = rsB;
  }
}

// ---------------------------------------------------------------------------
// Wo GEMM with fused K-split reduction + residual. A[row][kk] is materialized
// in LDS staging directly from po/rs partials: of = (sum_ks po) / (sum_ks rs).
// pre2 = of @ Wo^T + bo + x.  po ks-stride = 16*4096*16 = 1048576 floats.
__global__ __launch_bounds__(256) void wo_red_k(
    const float* __restrict__ po, const float* __restrict__ rs,
    const float* __restrict__ Wo, const float* __restrict__ bo,
    const float* __restrict__ xin, float* __restrict__ out)
{
  __shared__ __align__(16) float As[64][68];
  __shared__ __align__(16) float Ws[64][68];
  __shared__ float Linv[64][4];

  const int tid = threadIdx.x;
  const int rowbase = blockIdx.x * 64;
  const int r4 = (tid & 15) * 4;
  const int cg = (tid >> 4) * 4;

  // per-(row, head) inverse denominators
  {
    const int r = tid & 63, hb = tid >> 6;
    const int row = rowbase + r;
    const int bh = (row >> 12) * NH + hb;
    const int n = row & (NN - 1);
    const float s = rs[(size_t)bh * NN + n] + rs[(size_t)(16 + bh) * NN + n] +
                    rs[(size_t)(32 + bh) * NN + n] + rs[(size_t)(48 + bh) * NN + n];
    Linv[r][hb] = 1.f / s;
  }
  // stage Wo
  #pragma unroll
  for (int i = 0; i < 16; ++i) {
    int idx = tid + i * 256;
    int c2 = idx >> 6, kk = idx & 63;
    Ws[kk][c2] = Wo[(size_t)c2 * 64 + kk];
  }
  __syncthreads();
  // stage A = reduced+normalized attention output
  #pragma unroll
  for (int i = 0; i < 16; ++i) {
    int idx = tid + i * 256;
    int r = idx >> 6, kk = idx & 63;
    const int row = rowbase + r;
    const int bh = (row >> 12) * NH + (kk >> 4);
    const int n = row & (NN - 1);
    const int d = kk & 15;
    const size_t base = (((size_t)bh * NN + n) * DH) + d;
    const float v = po[base] + po[base + 1048576] +
                    po[base + 2097152] + po[base + 3145728];
    As[kk][r] = v * Linv[r][kk >> 4];
  }
  __syncthreads();

  float acc[4][4];
  #pragma unroll
  for (int i = 0; i < 4; ++i)
    #pragma unroll
    for (int j = 0; j < 4; ++j) acc[i][j] = 0.f;

  #pragma unroll 4
  for (int kk = 0; kk < 64; ++kk) {
    const float4 a = *(const float4*)&As[kk][r4];
    const float4 w4 = *(const float4*)&Ws[kk][cg];
    const float av[4] = {a.x, a.y, a.z, a.w};
    const float wv[4] = {w4.x, w4.y, w4.z, w4.w};
    #pragma unroll
    for (int ri = 0; ri < 4; ++ri)
      #pragma unroll
      for (int ci = 0; ci < 4; ++ci)
        acc[ri][ci] = fmaf(av[ri], wv[ci], acc[ri][ci]);
  }

  #pragma unroll
  for (int ri = 0; ri < 4; ++ri) {
    const int row = rowbase + r4 + ri;
    #pragma unroll
    for (int j = 0; j < 4; ++j) {
      const int c = cg + j;
      out[(size_t)row * CC + c] =
          acc[ri][j] + bo[c] + xin[(size_t)row * CC + c];
    }
  }
}

// ---------------------------------------------------------------------------
// Fused MLP: t = relu(h @ W1^T + b1) (kept in LDS), pre3 = t @ W2^T + b2m + h.
__global__ __launch_bounds__(256) void mlp_k(
    const float* __restrict__ hf, const float* __restrict__ W1,
    const float* __restrict__ b1, const float* __restrict__ W2,
    const float* __restrict__ b2m, float* __restrict__ out)
{
  __shared__ __align__(16) float As[64][68];     // h^T tile (k-major)
  __shared__ __align__(16) float Wbuf[8704];     // W1 [64][132] then W2 [128][68]
  __shared__ __align__(16) float Ts[128][68];    // relu(t)^T

  const int tid = threadIdx.x;
  const int rowbase = blockIdx.x * 64;
  const int r4 = (tid & 15) * 4;
  const int cg8 = (tid >> 4) * 8;    // phase 1 cols (128/16)
  const int cg4 = (tid >> 4) * 4;    // phase 2 cols (64/16)

  // stage h tile + W1
  #pragma unroll
  for (int i = 0; i < 32; ++i) {
    int idx = tid + i * 256;          // 8192 = 128c x 64k
    int c2 = idx >> 6, kk = idx & 63;
    Wbuf[kk * 132 + c2] = W1[(size_t)c2 * 64 + kk];
  }
  #pragma unroll
  for (int i = 0; i < 16; ++i) {
    int idx = tid + i * 256;
    int r = idx >> 6, kk = idx & 63;
    As[kk][r] = hf[(size_t)(rowbase + r) * CC + kk];
  }
  __syncthreads();

  // phase 1: t = relu(h @ W1^T + b1)
  float acc1[4][8];
  #pragma unroll
  for (int i = 0; i < 4; ++i)
    #pragma unroll
    for (int j = 0; j < 8; ++j) acc1[i][j] = 0.f;

  #pragma unroll 4
  for (int kk = 0; kk < 64; ++kk) {
    const float4 a = *(const float4*)&As[kk][r4];
    const float av[4] = {a.x, a.y, a.z, a.w};
    #pragma unroll
    for (int cj = 0; cj < 2; ++cj) {
      const float4 w4 = *(const float4*)&Wbuf[kk * 132 + cg8 + cj * 4];
      const float wv[4] = {w4.x, w4.y, w4.z, w4.w};
      #pragma unroll
      for (int ri = 0; ri < 4; ++ri)
        #pragma unroll
        for (int ci = 0; ci < 4; ++ci)
          acc1[ri][cj * 4 + ci] = fmaf(av[ri], wv[ci], acc1[ri][cj * 4 + ci]);
    }
  }
  #pragma unroll
  for (int ri = 0; ri < 4; ++ri)
    #pragma unroll
    for (int j = 0; j < 8; ++j)
      Ts[cg8 + j][r4 + ri] = fmaxf(acc1[ri][j] + b1[cg8 + j], 0.f);
  __syncthreads();

  // stage W2 over W1
  #pragma unroll
  for (int i = 0; i < 32; ++i) {
    int idx = tid + i * 256;          // 8192 = 64c x 128k
    int c2 = idx >> 7, kk = idx & 127;
    Wbuf[kk * 68 + c2] = W2[(size_t)c2 * 128 + kk];
  }
  __syncthreads();

  // phase 2: pre3 = t @ W2^T + b2m + h
  float acc2[4][4];
  #pragma unroll
  for (int i = 0; i < 4; ++i)
    #pragma unroll
    for (int j = 0; j < 4; ++j) acc2[i][j] = 0.f;

  #pragma unroll 4
  for (int kk = 0; kk < 128; ++kk) {
    const float4 a = *(const float4*)&Ts[kk][r4];
    const float4 w4 = *(const float4*)&Wbuf[kk * 68 + cg4];
    const float av[4] = {a.x, a.y, a.z, a.w};
    const float wv[4] = {w4.x, w4.y, w4.z, w4.w};
    #pragma unroll
    for (int ri = 0; ri < 4; ++ri)
      #pragma unroll
      for (int ci = 0; ci < 4; ++ci)
        acc2[ri][ci] = fmaf(av[ri], wv[ci], acc2[ri][ci]);
  }

  #pragma unroll
  for (int ri = 0; ri < 4; ++ri) {
    const int row = rowbase + r4 + ri;
    #pragma unroll
    for (int j = 0; j < 4; ++j) {
      const int c = cg4 + j;
      out[(size_t)row * CC + c] = acc2[ri][j] + b2m[c] + As[c][r4 + ri];
    }
  }
}

// ---------------------------------------------------------------------------
// BatchNorm over node axis, 4 channels per block (float4), biased var,
// EPS=1e-5, optional fused tanh. Grid 64 = 4 b x 16 channel-quads.
// In-place safe (each thread rewrites only elements it re-reads itself).
__global__ __launch_bounds__(256) void bn4_k(
    const float* __restrict__ in, const float* __restrict__ g,
    const float* __restrict__ b, float* __restrict__ out, int do_tanh)
{
  const int bb = blockIdx.x >> 4;
  const int c4 = (blockIdx.x & 15) * 4;
  const float* __restrict__ base = in + (size_t)bb * NN * CC + c4;
  const int tid = threadIdx.x;

  float4 s = {0, 0, 0, 0}, sq = {0, 0, 0, 0};
  #pragma unroll
  for (int i = 0; i < 16; ++i) {
    const float4 v = *(const float4*)&base[(size_t)(tid + i * 256) * CC];
    s.x += v.x; s.y += v.y; s.z += v.z; s.w += v.w;
    sq.x = fmaf(v.x, v.x, sq.x); sq.y = fmaf(v.y, v.y, sq.y);
    sq.z = fmaf(v.z, v.z, sq.z); sq.w = fmaf(v.w, v.w, sq.w);
  }
  #pragma unroll
  for (int off = 32; off; off >>= 1) {
    s.x += __shfl_down(s.x, off); s.y += __shfl_down(s.y, off);
    s.z += __shfl_down(s.z, off); s.w += __shfl_down(s.w, off);
    sq.x += __shfl_down(sq.x, off); sq.y += __shfl_down(sq.y, off);
    sq.z += __shfl_down(sq.z, off); sq.w += __shfl_down(sq.w, off);
  }
  __shared__ float red[4][8];
  const int wv = tid >> 6;
  if ((tid & 63) == 0) {
    red[wv][0] = s.x; red[wv][1] = s.y; red[wv][2] = s.z; red[wv][3] = s.w;
    red[wv][4] = sq.x; red[wv][5] = sq.y; red[wv][6] = sq.z; red[wv][7] = sq.w;
  }
  __syncthreads();
  float scale[4], shift[4];
  #pragma unroll
  for (int j = 0; j < 4; ++j) {
    const float ts = red[0][j] + red[1][j] + red[2][j] + red[3][j];
    const float tq = red[0][4 + j] + red[1][4 + j] + red[2][4 + j] + red[3][4 + j];
    const float mean = ts * (1.f / NN);
    const float var = tq * (1.f / NN) - mean * mean;
    const float rstd = rsqrtf(var + 1e-5f);
    scale[j] = g[c4 + j] * rstd;
    shift[j] = b[c4 + j] - mean * scale[j];
  }
  float* __restrict__ ob = out + (size_t)bb * NN * CC + c4;
  #pragma unroll
  for (int i = 0; i < 16; ++i) {
    const size_t idx = (size_t)(tid + i * 256) * CC;
    const float4 v = *(const float4*)&base[idx];
    float4 o;
    o.x = v.x * scale[0] + shift[0];
    o.y = v.y * scale[1] + shift[1];
    o.z = v.z * scale[2] + shift[2];
    o.w = v.w * scale[3] + shift[3];
    if (do_tanh) {
      o.x = fast_tanh(o.x); o.y = fast_tanh(o.y);
      o.z = fast_tanh(o.z); o.w = fast_tanh(o.w);
    }
    *(float4*)&ob[idx] = o;
  }
}

// ---------------------------------------------------------------------------
extern "C" void kernel_launch(void* const* d_in, const int* in_sizes, int n_in,
                              void* d_out, int out_size, void* d_ws, size_t ws_size,
                              hipStream_t stream)
{
  const float* inp  = (const float*)d_in[0];
  const float* Wp   = (const float*)d_in[2];
  const float* bp   = (const float*)d_in[3];
  const float* Wqkv = (const float*)d_in[4];
  const float* bqkv = (const float*)d_in[5];
  const float* Wo   = (const float*)d_in[6];
  const float* bo   = (const float*)d_in[7];
  const float* g2   = (const float*)d_in[8];
  const float* b2   = (const float*)d_in[9];
  const float* W1   = (const float*)d_in[10];
  const float* b1   = (const float*)d_in[11];
  const float* W2   = (const float*)d_in[12];
  const float* b2m  = (const float*)d_in[13];
  const float* g3   = (const float*)d_in[14];
  const float* b3   = (const float*)d_in[15];

  float* w = (float*)d_ws;
  float* x    = w;                 // [16384][64]   (dead after wo_red)
  float* qkvA = w + 1048576;       // f16 arena: q 0..1M, k 1M..2M, vt 2M..3M halves
  float* hf   = w + 2621440;       // pre2 -> (in-place bn) h
  float* pf   = w + 3670016;       // pre3 = h + mlp
  float* poW  = w + 4718592;       // attn partial O [4][16][4096][16]
  float* rsW  = w + 8912896;       // attn partial rowsums [4][16][4096]

  _Float16* f16b = (_Float16*)qkvA;

  proj_qkv_k<<<dim3(256), dim3(256), 0, stream>>>(inp, Wp, bp, Wqkv, bqkv, x, f16b);
  attn_k<<<dim3(2048), dim3(256), 0, stream>>>(f16b, f16b + 1048576,
                                               f16b + 2097152, poW, rsW);
  wo_red_k<<<dim3(256), dim3(256), 0, stream>>>(poW, rsW, Wo, bo, x, hf);
  bn4_k<<<dim3(64), dim3(256), 0, stream>>>(hf, g2, b2, hf, 0);
  mlp_k<<<dim3(256), dim3(256), 0, stream>>>(hf, W1, b1, W2, b2m, pf);
  bn4_k<<<dim3(64), dim3(256), 0, stream>>>(pf, g3, b3, (float*)d_out, 1);
}